// Round 12
// baseline (526.227 us; speedup 1.0000x reference)
//
#include <hip/hip_runtime.h>

typedef unsigned int uint;

#define N_NODES 100000
#define E_EDGES 1600000
#define L_LAYERS 3
#define G_GRAPHS 128
#define OUT_F 10
#define BN_EPS 1e-5f
#define NP1 (N_NODES + 1)

#define NB4 (N_NODES / 4)                 // 25000 int4 chunks
#define SCAN_BLOCKS ((NB4 + 255) / 256)   // 98
#define BSHIFT 7                          // 128-node stripes for XCD ownership
#define CHUNK 2048
#define NCHUNK ((E_EDGES + CHUNK - 1) / CHUNK)   // 782
#define PAD8(d) (((d) + 7) & ~7)
#define GATHER_BLOCKS (782 * 8)           // 4 colgroups x 1564 row-blocks

// bf16 pack (RTNE) / unpack helpers
__device__ __forceinline__ uint bf_pack(float a, float b) {
    uint ua = __float_as_uint(a);
    ua = (ua + 0x7fffu + ((ua >> 16) & 1u)) >> 16;
    uint ub = __float_as_uint(b);
    ub = (ub + 0x7fffu + ((ub >> 16) & 1u)) >> 16;
    return ua | (ub << 16);
}
__device__ __forceinline__ unsigned short bf1(float a) {
    uint ua = __float_as_uint(a);
    return (unsigned short)((ua + 0x7fffu + ((ua >> 16) & 1u)) >> 16);
}
__device__ __forceinline__ float lo16(uint u) { return __uint_as_float(u << 16); }
__device__ __forceinline__ float hi16(uint u) { return __uint_as_float(u & 0xffff0000u); }

// -------------------- CSR build: degree histogram (int4) -----------------
__global__ __launch_bounds__(256) void deg_kernel(const int* __restrict__ dst,
                                                  int* __restrict__ deg) {
    int i = blockIdx.x * blockDim.x + threadIdx.x;   // E/4 threads
    if (i < E_EDGES / 4) {
        int4 d = reinterpret_cast<const int4*>(dst)[i];
        atomicAdd(&deg[d.x], 1);
        atomicAdd(&deg[d.y], 1);
        atomicAdd(&deg[d.z], 1);
        atomicAdd(&deg[d.w], 1);
    }
}

// -------------------- scan phase A: per-block sums (padded degrees) ------
__global__ __launch_bounds__(256) void scanA_kernel(const int* __restrict__ deg,
                                                    int* __restrict__ bsum) {
    __shared__ int red[256];
    int t = threadIdx.x;
    int i4 = blockIdx.x * 256 + t;
    int s = 0;
    if (i4 < NB4) {
        int4 v = reinterpret_cast<const int4*>(deg)[i4];
        s = PAD8(v.x) + PAD8(v.y) + PAD8(v.z) + PAD8(v.w);
    }
    red[t] = s;
    __syncthreads();
    for (int off = 128; off > 0; off >>= 1) {
        if (t < off) red[t] += red[t + off];
        __syncthreads();
    }
    if (t == 0) bsum[blockIdx.x] = red[0];
}

// -------------------- scan phase B: scan the block sums ------------------
__global__ __launch_bounds__(128) void scanB_kernel(int* __restrict__ bsum,
                                                    int* __restrict__ rowptr) {
    __shared__ int p[128];
    int t = threadIdx.x;
    int v = (t < SCAN_BLOCKS) ? bsum[t] : 0;
    p[t] = v;
    __syncthreads();
    for (int off = 1; off < 128; off <<= 1) {
        int u = (t >= off) ? p[t - off] : 0;
        __syncthreads();
        p[t] += u;
        __syncthreads();
    }
    if (t < SCAN_BLOCKS) bsum[t] = p[t] - v;      // exclusive block offset
    if (t == 127) rowptr[N_NODES] = p[127];       // total (padded)
}

// ---------- scan phase C: write padded rowptr + cursor --------------------
__global__ __launch_bounds__(256) void scanC_kernel(
    const int* __restrict__ deg, const int* __restrict__ bsum,
    int* __restrict__ rowptr, int* __restrict__ cursor) {
    __shared__ int ts[256];
    int t = threadIdx.x;
    int i4 = blockIdx.x * 256 + t;
    int4 v = make_int4(0, 0, 0, 0);
    if (i4 < NB4) v = reinterpret_cast<const int4*>(deg)[i4];
    int4 pv = make_int4(PAD8(v.x), PAD8(v.y), PAD8(v.z), PAD8(v.w));
    int s = pv.x + pv.y + pv.z + pv.w;
    ts[t] = s;
    __syncthreads();
    for (int off = 1; off < 256; off <<= 1) {
        int u = (t >= off) ? ts[t - off] : 0;
        __syncthreads();
        ts[t] += u;
        __syncthreads();
    }
    if (i4 < NB4) {
        int base = bsum[blockIdx.x] + ts[t] - s;   // exclusive prefix
        int4 rp;
        rp.x = base;
        rp.y = rp.x + pv.x;
        rp.z = rp.y + pv.y;
        rp.w = rp.z + pv.z;
        reinterpret_cast<int4*>(rowptr)[i4] = rp;
        reinterpret_cast<int4*>(cursor)[i4] = rp;
    }
}

// ------------- CSR fill: XCD-striped scatter ------------------------------
__global__ __launch_bounds__(256) void fill_kernel(
    const int* __restrict__ src, const int* __restrict__ dst,
    int* __restrict__ cursor, int* __restrict__ nbr) {
    int xcd = blockIdx.x & 7;
    int base = (blockIdx.x >> 3) * CHUNK;
    #pragma unroll
    for (int it = 0; it < CHUNK / 256; ++it) {
        int e = base + it * 256 + threadIdx.x;
        if (e < E_EDGES) {
            int d = dst[e];
            if (((d >> BSHIFT) & 7) == xcd) {
                int pos = atomicAdd(&cursor[d], 1);
                nbr[pos] = src[e];
            }
        }
    }
}

// ---------- pad tail of each segment with sentinel row N ------------------
__global__ __launch_bounds__(256) void pad_kernel(
    const int* __restrict__ rowptr, const int* __restrict__ deg,
    int* __restrict__ nbr) {
    int i = blockIdx.x * 256 + threadIdx.x;
    if (i < N_NODES) {
        int b = rowptr[i] + deg[i];
        int e = rowptr[i + 1];
        for (int j = b; j < e; ++j) nbr[j] = N_NODES;   // zero sentinel row
    }
}

// ----- x f32 -> bf16, column-blocked [4][N+1][16] (layer 0 only) ----------
__global__ __launch_bounds__(256) void tobf_kernel(const float* __restrict__ x,
                                                   uint* __restrict__ xbf) {
    int i = blockIdx.x * 256 + threadIdx.x;   // N*8 threads, 8 floats each
    if (i < N_NODES * 8) {
        int row = i >> 3, part = i & 7;
        int c0 = part * 8;
        int g = c0 >> 4, w = c0 & 15;          // w in {0,8}
        float4 a = reinterpret_cast<const float4*>(x)[i * 2];
        float4 b = reinterpret_cast<const float4*>(x)[i * 2 + 1];
        uint4 o;
        o.x = bf_pack(a.x, a.y);
        o.y = bf_pack(a.z, a.w);
        o.z = bf_pack(b.x, b.y);
        o.w = bf_pack(b.z, b.w);
        reinterpret_cast<uint4*>(xbf)[((size_t)g * NP1 + row) * 2 + (w >> 3)] = o;
    }
    if (i < 4) {                               // zero the 4 per-group sentinel rows
        uint4 z = make_uint4(0, 0, 0, 0);
        reinterpret_cast<uint4*>(xbf)[((size_t)i * NP1 + N_NODES) * 2] = z;
        reinterpret_cast<uint4*>(xbf)[((size_t)i * NP1 + N_NODES) * 2 + 1] = z;
    }
}

// ------ gather: agg[g][i][0:16] = x[g][i] + sum_nbr x[g][nbr] -------------
// blocks: b&7 -> XCD (dispatch heuristic); XCD pair {2g,2g+1} serves colgroup
// g only -> its 3.2MB sub-array stays L2-resident. 4 lanes/row (8B each).
__global__ __launch_bounds__(256) void gather_kernel(
    const uint* __restrict__ xbf, const int* __restrict__ rowptr,
    const int* __restrict__ nbr, uint* __restrict__ agg) {
    int b = blockIdx.x;
    int g = (b >> 1) & 3;                       // colgroup from XCD pair
    int rb = ((b >> 3) << 1) | (b & 1);         // row-block within colgroup
    int row0 = rb * 64;
    if (row0 >= N_NODES) return;
    int tid = threadIdx.x;
    int r = tid >> 2, lane = tid & 3;
    int gr = row0 + r;
    if (gr >= N_NODES) return;                  // no LDS/sync in this kernel

    const uint2* xb2 = reinterpret_cast<const uint2*>(xbf);
    size_t gbase = (size_t)g * NP1;
    uint2 sv = xb2[(gbase + gr) * 4 + lane];
    float a0 = lo16(sv.x), a1 = hi16(sv.x), a2 = lo16(sv.y), a3 = hi16(sv.y);

    int beg = rowptr[gr], end = rowptr[gr + 1];
    for (int j = beg; j < end; j += 8) {
        int4 ia = *reinterpret_cast<const int4*>(nbr + j);
        int4 ib = *reinterpret_cast<const int4*>(nbr + j + 4);
        uint2 v0 = xb2[(gbase + ia.x) * 4 + lane];
        uint2 v1 = xb2[(gbase + ia.y) * 4 + lane];
        uint2 v2 = xb2[(gbase + ia.z) * 4 + lane];
        uint2 v3 = xb2[(gbase + ia.w) * 4 + lane];
        uint2 v4 = xb2[(gbase + ib.x) * 4 + lane];
        uint2 v5 = xb2[(gbase + ib.y) * 4 + lane];
        uint2 v6 = xb2[(gbase + ib.z) * 4 + lane];
        uint2 v7 = xb2[(gbase + ib.w) * 4 + lane];
        a0 += lo16(v0.x); a1 += hi16(v0.x); a2 += lo16(v0.y); a3 += hi16(v0.y);
        a0 += lo16(v1.x); a1 += hi16(v1.x); a2 += lo16(v1.y); a3 += hi16(v1.y);
        a0 += lo16(v2.x); a1 += hi16(v2.x); a2 += lo16(v2.y); a3 += hi16(v2.y);
        a0 += lo16(v3.x); a1 += hi16(v3.x); a2 += lo16(v3.y); a3 += hi16(v3.y);
        a0 += lo16(v4.x); a1 += hi16(v4.x); a2 += lo16(v4.y); a3 += hi16(v4.y);
        a0 += lo16(v5.x); a1 += hi16(v5.x); a2 += lo16(v5.y); a3 += hi16(v5.y);
        a0 += lo16(v6.x); a1 += hi16(v6.x); a2 += lo16(v6.y); a3 += hi16(v6.y);
        a0 += lo16(v7.x); a1 += hi16(v7.x); a2 += lo16(v7.y); a3 += hi16(v7.y);
    }
    uint2 o;
    o.x = bf_pack(a0, a1);
    o.y = bf_pack(a2, a3);
    reinterpret_cast<uint2*>(agg)[(gbase + gr) * 4 + lane] = o;
}

// ------- GEMM1 (4x4 tile) + BN stats: h = agg @ W1 + b1 -------------------
__global__ __launch_bounds__(256) void gemm1_kernel(
    const uint* __restrict__ agg, const float* __restrict__ W1,
    const float* __restrict__ b1, unsigned short* __restrict__ h16,
    float* __restrict__ stats) {
    __shared__ float sA[64][68];                 // +4 pad: 2-way bank alias (free)
    __shared__ unsigned short sWh[64][64];
    int tid = threadIdx.x;
    int row0 = blockIdx.x * 64;

    for (int i = tid; i < 1024; i += 256) {
        float4 w = reinterpret_cast<const float4*>(W1)[i];
        unsigned short* p = &sWh[0][0] + i * 4;
        p[0] = bf1(w.x); p[1] = bf1(w.y); p[2] = bf1(w.z); p[3] = bf1(w.w);
    }

    // stage agg tile from column-blocked layout
    const uint4* ag4 = reinterpret_cast<const uint4*>(agg);
    for (int i = tid; i < 512; i += 256) {
        int g = i >> 7, rem = i & 127, r = rem >> 1, half = rem & 1;
        int gr = row0 + r;
        float4 f0 = make_float4(0.f, 0.f, 0.f, 0.f);
        float4 f1 = make_float4(0.f, 0.f, 0.f, 0.f);
        if (gr < N_NODES) {
            uint4 v = ag4[((size_t)g * NP1 + gr) * 2 + half];
            f0 = make_float4(lo16(v.x), hi16(v.x), lo16(v.y), hi16(v.y));
            f1 = make_float4(lo16(v.z), hi16(v.z), lo16(v.w), hi16(v.w));
        }
        int cb = g * 16 + half * 8;
        *reinterpret_cast<float4*>(&sA[r][cb]) = f0;
        *reinterpret_cast<float4*>(&sA[r][cb + 4]) = f1;
    }
    __syncthreads();

    // 4x4 register-tiled GEMM
    int ct = tid & 15, rt = tid >> 4;
    int cbase = ct * 4, rbase = rt * 4;
    float4 bias = reinterpret_cast<const float4*>(b1)[ct];
    float acc[4][4];
    #pragma unroll
    for (int i = 0; i < 4; ++i) {
        acc[i][0] = bias.x; acc[i][1] = bias.y; acc[i][2] = bias.z; acc[i][3] = bias.w;
    }
    for (int k = 0; k < 64; ++k) {
        float A0 = sA[rbase + 0][k], A1 = sA[rbase + 1][k];
        float A2 = sA[rbase + 2][k], A3 = sA[rbase + 3][k];
        uint2 wp = *reinterpret_cast<const uint2*>(&sWh[k][cbase]);
        float w0 = lo16(wp.x), w1 = hi16(wp.x), w2 = lo16(wp.y), w3 = hi16(wp.y);
        acc[0][0] = fmaf(A0, w0, acc[0][0]); acc[0][1] = fmaf(A0, w1, acc[0][1]);
        acc[0][2] = fmaf(A0, w2, acc[0][2]); acc[0][3] = fmaf(A0, w3, acc[0][3]);
        acc[1][0] = fmaf(A1, w0, acc[1][0]); acc[1][1] = fmaf(A1, w1, acc[1][1]);
        acc[1][2] = fmaf(A1, w2, acc[1][2]); acc[1][3] = fmaf(A1, w3, acc[1][3]);
        acc[2][0] = fmaf(A2, w0, acc[2][0]); acc[2][1] = fmaf(A2, w1, acc[2][1]);
        acc[2][2] = fmaf(A2, w2, acc[2][2]); acc[2][3] = fmaf(A2, w3, acc[2][3]);
        acc[3][0] = fmaf(A3, w0, acc[3][0]); acc[3][1] = fmaf(A3, w1, acc[3][1]);
        acc[3][2] = fmaf(A3, w2, acc[3][2]); acc[3][3] = fmaf(A3, w3, acc[3][3]);
    }

    float csum[4] = {0.f, 0.f, 0.f, 0.f};
    float csq[4]  = {0.f, 0.f, 0.f, 0.f};
    #pragma unroll
    for (int i = 0; i < 4; ++i) {
        int gr = row0 + rbase + i;
        if (gr < N_NODES) {
            uint2 o;
            o.x = bf_pack(acc[i][0], acc[i][1]);
            o.y = bf_pack(acc[i][2], acc[i][3]);
            *reinterpret_cast<uint2*>(&h16[(size_t)gr * 64 + cbase]) = o;
            #pragma unroll
            for (int j = 0; j < 4; ++j) {
                csum[j] += acc[i][j];
                csq[j]  += acc[i][j] * acc[i][j];
            }
        }
    }
    __syncthreads();                     // sA reads done; reuse as scratch
    float* scratch = &sA[0][0];
    #pragma unroll
    for (int j = 0; j < 4; ++j) {
        scratch[rt * 136 + cbase + j]      = csum[j];
        scratch[rt * 136 + 64 + cbase + j] = csq[j];
    }
    __syncthreads();
    if (tid < 64) {
        float s = 0.f, q = 0.f;
        #pragma unroll
        for (int r2 = 0; r2 < 16; ++r2) {
            s += scratch[r2 * 136 + tid];
            q += scratch[r2 * 136 + 64 + tid];
        }
        unsafeAtomicAdd(&stats[tid], s);
        unsafeAtomicAdd(&stats[64 + tid], q);
    }
}

// -- GEMM2(4x4) + pool: xn=relu(bn(h))@W2+b2; pooled+=xn; xn->col-blocked --
__global__ __launch_bounds__(256) void gemm2_pool_kernel(
    const unsigned short* __restrict__ h16, const float* __restrict__ stats,
    const float* __restrict__ gamma, const float* __restrict__ beta,
    const float* __restrict__ W2, const float* __restrict__ b2,
    const int* __restrict__ batch, float* __restrict__ pooled,
    uint* __restrict__ xout) {
    __shared__ float sA[64][68];
    __shared__ unsigned short sWh[64][64];
    int tid = threadIdx.x;
    int row0 = blockIdx.x * 64;

    for (int i = tid; i < 1024; i += 256) {
        float4 w = reinterpret_cast<const float4*>(W2)[i];
        unsigned short* p = &sWh[0][0] + i * 4;
        p[0] = bf1(w.x); p[1] = bf1(w.y); p[2] = bf1(w.z); p[3] = bf1(w.w);
    }

    // per-thread BN scale/shift for its fixed 8 staging columns
    int c8 = tid & 7;
    float scv[8], shv[8];
    #pragma unroll
    for (int k = 0; k < 8; ++k) {
        int col = c8 * 8 + k;
        float mu = stats[col] * (1.0f / N_NODES);
        float var = stats[64 + col] * (1.0f / N_NODES) - mu * mu;
        scv[k] = gamma[col] * rsqrtf(var + BN_EPS);
        shv[k] = beta[col] - mu * scv[k];
    }

    const uint4* h4 = reinterpret_cast<const uint4*>(h16);
    for (int i = tid; i < 512; i += 256) {
        int r = i >> 3;                    // (i&7) == c8 since 256 % 8 == 0
        int gr = row0 + r;
        float o[8] = {0.f, 0.f, 0.f, 0.f, 0.f, 0.f, 0.f, 0.f};
        if (gr < N_NODES) {
            uint4 v = h4[(size_t)gr * 8 + c8];
            float f[8] = {lo16(v.x), hi16(v.x), lo16(v.y), hi16(v.y),
                          lo16(v.z), hi16(v.z), lo16(v.w), hi16(v.w)};
            #pragma unroll
            for (int k = 0; k < 8; ++k)
                o[k] = fmaxf(fmaf(f[k], scv[k], shv[k]), 0.f);
        }
        *reinterpret_cast<float4*>(&sA[r][c8 * 8]) = make_float4(o[0], o[1], o[2], o[3]);
        *reinterpret_cast<float4*>(&sA[r][c8 * 8 + 4]) = make_float4(o[4], o[5], o[6], o[7]);
    }
    __syncthreads();

    int ct = tid & 15, rt = tid >> 4;
    int cbase = ct * 4, rbase = rt * 4;
    float4 bias = reinterpret_cast<const float4*>(b2)[ct];
    float acc[4][4];
    #pragma unroll
    for (int i = 0; i < 4; ++i) {
        acc[i][0] = bias.x; acc[i][1] = bias.y; acc[i][2] = bias.z; acc[i][3] = bias.w;
    }
    for (int k = 0; k < 64; ++k) {
        float A0 = sA[rbase + 0][k], A1 = sA[rbase + 1][k];
        float A2 = sA[rbase + 2][k], A3 = sA[rbase + 3][k];
        uint2 wp = *reinterpret_cast<const uint2*>(&sWh[k][cbase]);
        float w0 = lo16(wp.x), w1 = hi16(wp.x), w2 = lo16(wp.y), w3 = hi16(wp.y);
        acc[0][0] = fmaf(A0, w0, acc[0][0]); acc[0][1] = fmaf(A0, w1, acc[0][1]);
        acc[0][2] = fmaf(A0, w2, acc[0][2]); acc[0][3] = fmaf(A0, w3, acc[0][3]);
        acc[1][0] = fmaf(A1, w0, acc[1][0]); acc[1][1] = fmaf(A1, w1, acc[1][1]);
        acc[1][2] = fmaf(A1, w2, acc[1][2]); acc[1][3] = fmaf(A1, w3, acc[1][3]);
        acc[2][0] = fmaf(A2, w0, acc[2][0]); acc[2][1] = fmaf(A2, w1, acc[2][1]);
        acc[2][2] = fmaf(A2, w2, acc[2][2]); acc[2][3] = fmaf(A2, w3, acc[2][3]);
        acc[3][0] = fmaf(A3, w0, acc[3][0]); acc[3][1] = fmaf(A3, w1, acc[3][1]);
        acc[3][2] = fmaf(A3, w2, acc[3][2]); acc[3][3] = fmaf(A3, w3, acc[3][3]);
    }

    // write xout (bf16, column-blocked [4][N+1][16])
    int gg = cbase >> 4, w = cbase & 15;
    #pragma unroll
    for (int i = 0; i < 4; ++i) {
        int gr = row0 + rbase + i;
        if (gr < N_NODES) {
            uint2 o;
            o.x = bf_pack(acc[i][0], acc[i][1]);
            o.y = bf_pack(acc[i][2], acc[i][3]);
            reinterpret_cast<uint2*>(xout)[((size_t)gg * NP1 + gr) * 4 + (w >> 2)] = o;
        }
    }

    // pool: single-graph block -> LDS reduce + 1 atomic/col; else run-length
    int lastrow = row0 + 63; if (lastrow >= N_NODES) lastrow = N_NODES - 1;
    int b0 = batch[row0], bL = batch[lastrow];
    if (b0 == bL) {
        float psum[4] = {0.f, 0.f, 0.f, 0.f};
        #pragma unroll
        for (int i = 0; i < 4; ++i) {
            int gr = row0 + rbase + i;
            if (gr < N_NODES) {
                #pragma unroll
                for (int j = 0; j < 4; ++j) psum[j] += acc[i][j];
            }
        }
        __syncthreads();                 // sA reads done; reuse as scratch
        float* scratch = &sA[0][0];
        #pragma unroll
        for (int j = 0; j < 4; ++j) scratch[rt * 68 + cbase + j] = psum[j];
        __syncthreads();
        if (tid < 64) {
            float s = 0.f;
            #pragma unroll
            for (int r2 = 0; r2 < 16; ++r2) s += scratch[r2 * 68 + tid];
            unsafeAtomicAdd(&pooled[b0 * 64 + tid], s);
        }
    } else {
        #pragma unroll
        for (int j = 0; j < 4; ++j) {
            float pacc = 0.f;
            int curb = -1;
            #pragma unroll
            for (int i = 0; i < 4; ++i) {
                int gr = row0 + rbase + i;
                if (gr < N_NODES) {
                    int b = batch[gr];
                    if (b != curb) {
                        if (curb >= 0) unsafeAtomicAdd(&pooled[curb * 64 + cbase + j], pacc);
                        curb = b;
                        pacc = 0.f;
                    }
                    pacc += acc[i][j];
                }
            }
            if (curb >= 0) unsafeAtomicAdd(&pooled[curb * 64 + cbase + j], pacc);
        }
    }
}

// -------------------- output: score += pooled @ Wout + bout --------------
__global__ void out_kernel(const float* __restrict__ pooled,
                           const float* __restrict__ Wout,
                           const float* __restrict__ bout,
                           float* __restrict__ score) {
    int idx = blockIdx.x * blockDim.x + threadIdx.x;
    if (idx >= G_GRAPHS * OUT_F) return;
    int g = idx / OUT_F;
    int o = idx - g * OUT_F;
    float acc = bout[o];
    #pragma unroll
    for (int k = 0; k < 64; ++k) acc += pooled[g * 64 + k] * Wout[k * OUT_F + o];
    score[idx] += acc;
}

extern "C" void kernel_launch(void* const* d_in, const int* in_sizes, int n_in,
                              void* d_out, int out_size, void* d_ws, size_t ws_size,
                              hipStream_t stream) {
    const float* x     = (const float*)d_in[0];
    const int*   ei    = (const int*)d_in[1];
    const int*   batch = (const int*)d_in[2];
    const float* W1    = (const float*)d_in[3];
    const float* b1    = (const float*)d_in[4];
    const float* gamma = (const float*)d_in[5];
    const float* beta  = (const float*)d_in[6];
    const float* W2    = (const float*)d_in[7];
    const float* b2    = (const float*)d_in[8];
    const float* Wout  = (const float*)d_in[9];
    const float* bout  = (const float*)d_in[10];
    float* out = (float*)d_out;

    unsigned short* H16 = (unsigned short*)d_ws;             // N*64 bf16
    uint*  XBF    = (uint*)(H16 + (size_t)N_NODES * 64);     // 4*NP1*8 uints (col-blocked)
    uint*  AGG    = XBF + (size_t)4 * NP1 * 8;               // 4*NP1*8 uints (col-blocked)
    float* stats  = (float*)(AGG + (size_t)4 * NP1 * 8);     // 128
    float* pooled = stats + 128;                             // G*64 (adjacent)
    int*   deg    = (int*)(pooled + (size_t)G_GRAPHS * 64);  // N
    int*   rowptr = deg + N_NODES;                           // N+4
    int*   cursor = rowptr + N_NODES + 4;                    // N
    int*   bsum   = cursor + N_NODES;                        // SCAN_BLOCKS (pad 128)
    int*   nbr    = bsum + 128;                              // E + 8N (padded CSR)

    const int* src = ei;
    const int* dst = ei + E_EDGES;

    (void)hipMemsetAsync(d_out, 0, (size_t)G_GRAPHS * OUT_F * sizeof(float), stream);
    (void)hipMemsetAsync(deg, 0, (size_t)N_NODES * sizeof(int), stream);

    deg_kernel<<<(E_EDGES / 4 + 255) / 256, 256, 0, stream>>>(dst, deg);
    scanA_kernel<<<SCAN_BLOCKS, 256, 0, stream>>>(deg, bsum);
    scanB_kernel<<<1, 128, 0, stream>>>(bsum, rowptr);
    scanC_kernel<<<SCAN_BLOCKS, 256, 0, stream>>>(deg, bsum, rowptr, cursor);
    fill_kernel<<<NCHUNK * 8, 256, 0, stream>>>(src, dst, cursor, nbr);
    pad_kernel<<<(N_NODES + 255) / 256, 256, 0, stream>>>(rowptr, deg, nbr);
    tobf_kernel<<<(N_NODES * 8 + 255) / 256, 256, 0, stream>>>(x, XBF);

    int nb = (N_NODES + 63) / 64;

    for (int l = 0; l < L_LAYERS; ++l) {
        // stats (128) + pooled (G*64) are adjacent: one memset
        (void)hipMemsetAsync(stats, 0, (128 + (size_t)G_GRAPHS * 64) * sizeof(float), stream);

        gather_kernel<<<GATHER_BLOCKS, 256, 0, stream>>>(XBF, rowptr, nbr, AGG);
        gemm1_kernel<<<nb, 256, 0, stream>>>(AGG, W1 + l * 64 * 64, b1 + l * 64, H16, stats);
        gemm2_pool_kernel<<<nb, 256, 0, stream>>>(H16, stats,
            gamma + l * 64, beta + l * 64, W2 + l * 64 * 64, b2 + l * 64, batch,
            pooled, XBF);
        out_kernel<<<(G_GRAPHS * OUT_F + 127) / 128, 128, 0, stream>>>(
            pooled, Wout + l * 64 * OUT_F, bout + l * OUT_F, out);
    }
}

// Round 13
// 463.553 us; speedup vs baseline: 1.1352x; 1.1352x over previous
//
#include <hip/hip_runtime.h>

typedef unsigned int uint;
typedef int iv4 __attribute__((ext_vector_type(4)));

#define N_NODES 100000
#define E_EDGES 1600000
#define L_LAYERS 3
#define G_GRAPHS 128
#define OUT_F 10
#define BN_EPS 1e-5f

#define NB4 (N_NODES / 4)                 // 25000 int4 chunks
#define SCAN_BLOCKS ((NB4 + 255) / 256)   // 98
#define BSHIFT 7                          // 128-node stripes for XCD ownership
#define CHUNK 2048
#define NCHUNK ((E_EDGES + CHUNK - 1) / CHUNK)   // 782
#define PAD8(d) (((d) + 7) & ~7)
#define BCAP (2048 * 103)                 // per-XCD edge queue capacity (~26 sd slack)
#define FB_GRID (103 * 8)

// bf16 pack (RTNE) / unpack helpers
__device__ __forceinline__ uint bf_pack(float a, float b) {
    uint ua = __float_as_uint(a);
    ua = (ua + 0x7fffu + ((ua >> 16) & 1u)) >> 16;
    uint ub = __float_as_uint(b);
    ub = (ub + 0x7fffu + ((ub >> 16) & 1u)) >> 16;
    return ua | (ub << 16);
}
__device__ __forceinline__ unsigned short bf1(float a) {
    uint ua = __float_as_uint(a);
    return (unsigned short)((ua + 0x7fffu + ((ua >> 16) & 1u)) >> 16);
}
__device__ __forceinline__ float lo16(uint u) { return __uint_as_float(u << 16); }
__device__ __forceinline__ float hi16(uint u) { return __uint_as_float(u & 0xffff0000u); }

// -------------------- CSR build: degree histogram (int4, nt loads) -------
__global__ __launch_bounds__(256) void deg_kernel(const int* __restrict__ dst,
                                                  int* __restrict__ deg) {
    int i = blockIdx.x * blockDim.x + threadIdx.x;   // E/4 threads
    if (i < E_EDGES / 4) {
        iv4 d = __builtin_nontemporal_load(reinterpret_cast<const iv4*>(dst) + i);
        atomicAdd(&deg[d.x], 1);
        atomicAdd(&deg[d.y], 1);
        atomicAdd(&deg[d.z], 1);
        atomicAdd(&deg[d.w], 1);
    }
}

// -------------------- scan phase A: per-block sums (padded degrees) ------
__global__ __launch_bounds__(256) void scanA_kernel(const int* __restrict__ deg,
                                                    int* __restrict__ bsum) {
    __shared__ int red[256];
    int t = threadIdx.x;
    int i4 = blockIdx.x * 256 + t;
    int s = 0;
    if (i4 < NB4) {
        int4 v = reinterpret_cast<const int4*>(deg)[i4];
        s = PAD8(v.x) + PAD8(v.y) + PAD8(v.z) + PAD8(v.w);
    }
    red[t] = s;
    __syncthreads();
    for (int off = 128; off > 0; off >>= 1) {
        if (t < off) red[t] += red[t + off];
        __syncthreads();
    }
    if (t == 0) bsum[blockIdx.x] = red[0];
}

// ------------- scan phase B: scan block sums; init bucket cursors --------
__global__ __launch_bounds__(128) void scanB_kernel(int* __restrict__ bsum,
                                                    int* __restrict__ rowptr,
                                                    int* __restrict__ gcur) {
    __shared__ int p[128];
    int t = threadIdx.x;
    int v = (t < SCAN_BLOCKS) ? bsum[t] : 0;
    p[t] = v;
    __syncthreads();
    for (int off = 1; off < 128; off <<= 1) {
        int u = (t >= off) ? p[t - off] : 0;
        __syncthreads();
        p[t] += u;
        __syncthreads();
    }
    if (t < SCAN_BLOCKS) bsum[t] = p[t] - v;      // exclusive block offset
    if (t == 127) rowptr[N_NODES] = p[127];       // total (padded)
    if (t < 8) gcur[t] = t * BCAP;                // per-XCD queue bases
}

// ---------- scan phase C: write padded rowptr + cursor --------------------
__global__ __launch_bounds__(256) void scanC_kernel(
    const int* __restrict__ deg, const int* __restrict__ bsum,
    int* __restrict__ rowptr, int* __restrict__ cursor) {
    __shared__ int ts[256];
    int t = threadIdx.x;
    int i4 = blockIdx.x * 256 + t;
    int4 v = make_int4(0, 0, 0, 0);
    if (i4 < NB4) v = reinterpret_cast<const int4*>(deg)[i4];
    int4 pv = make_int4(PAD8(v.x), PAD8(v.y), PAD8(v.z), PAD8(v.w));
    int s = pv.x + pv.y + pv.z + pv.w;
    ts[t] = s;
    __syncthreads();
    for (int off = 1; off < 256; off <<= 1) {
        int u = (t >= off) ? ts[t - off] : 0;
        __syncthreads();
        ts[t] += u;
        __syncthreads();
    }
    if (i4 < NB4) {
        int base = bsum[blockIdx.x] + ts[t] - s;   // exclusive prefix
        int4 rp;
        rp.x = base;
        rp.y = rp.x + pv.x;
        rp.z = rp.y + pv.y;
        rp.w = rp.z + pv.z;
        reinterpret_cast<int4*>(rowptr)[i4] = rp;
        reinterpret_cast<int4*>(cursor)[i4] = rp;
    }
}

// ---- fill pass A: bin edges into 8 per-XCD queues (single read of ei) ----
__global__ __launch_bounds__(256) void fillA_kernel(
    const int* __restrict__ src, const int* __restrict__ dst,
    int* __restrict__ gcur, int2* __restrict__ epair) {
    __shared__ int lcnt[8];
    __shared__ int lbase[8];
    int tid = threadIdx.x;
    int base = blockIdx.x * CHUNK;
    if (tid < 8) lcnt[tid] = 0;
    __syncthreads();

    int sd[8], ss[8], bk[8], off[8];
    #pragma unroll
    for (int it = 0; it < 8; ++it) {
        int e = base + it * 256 + tid;
        bk[it] = -1;
        if (e < E_EDGES) {
            sd[it] = dst[e];
            ss[it] = src[e];
            bk[it] = (sd[it] >> BSHIFT) & 7;
            off[it] = atomicAdd(&lcnt[bk[it]], 1);
        }
    }
    __syncthreads();
    if (tid < 8) lbase[tid] = atomicAdd(&gcur[tid], lcnt[tid]);
    __syncthreads();
    #pragma unroll
    for (int it = 0; it < 8; ++it) {
        if (bk[it] >= 0)
            epair[lbase[bk[it]] + off[it]] = make_int2(ss[it], sd[it]);
    }
}

// ---- fill pass B: XCD-local scatter from the XCD's own queue -------------
__global__ __launch_bounds__(256) void fillB_kernel(
    const int2* __restrict__ epair, const int* __restrict__ gcur,
    int* __restrict__ cursor, int* __restrict__ nbr) {
    int g = blockIdx.x & 7;                     // bucket == XCD (b&7 heuristic)
    int c = blockIdx.x >> 3;
    int ebeg = g * BCAP + c * CHUNK;
    int eend = gcur[g];                         // base + count after pass A
    #pragma unroll
    for (int it = 0; it < CHUNK / 256; ++it) {
        int i = ebeg + it * 256 + threadIdx.x;
        if (i < eend) {
            int2 p = epair[i];
            int pos = atomicAdd(&cursor[p.y], 1);
            nbr[pos] = p.x;
        }
    }
}

// ---------- pad tail of each segment with sentinel row N ------------------
__global__ __launch_bounds__(256) void pad_kernel(
    const int* __restrict__ rowptr, const int* __restrict__ deg,
    int* __restrict__ nbr) {
    int i = blockIdx.x * 256 + threadIdx.x;
    if (i < N_NODES) {
        int b = rowptr[i] + deg[i];
        int e = rowptr[i + 1];
        for (int j = b; j < e; ++j) nbr[j] = N_NODES;   // zero sentinel row
    }
}

// -------------------- x f32 -> bf16 (layer 0 only) ------------------------
__global__ __launch_bounds__(256) void tobf_kernel(const float* __restrict__ x,
                                                   uint* __restrict__ xbf) {
    int i = blockIdx.x * 256 + threadIdx.x;   // N*8 threads, 8 floats each
    if (i < N_NODES * 8) {
        float4 a = reinterpret_cast<const float4*>(x)[i * 2];
        float4 b = reinterpret_cast<const float4*>(x)[i * 2 + 1];
        uint4 o;
        o.x = bf_pack(a.x, a.y);
        o.y = bf_pack(a.z, a.w);
        o.z = bf_pack(b.x, b.y);
        o.w = bf_pack(b.z, b.w);
        reinterpret_cast<uint4*>(xbf)[i] = o;
    }
    if (i < 8) reinterpret_cast<uint4*>(xbf)[N_NODES * 8 + i] = make_uint4(0, 0, 0, 0);
}

// ------- fused gather(bf16, padded CSR, idx-prefetch) + GEMM1 + stats -----
__global__ __launch_bounds__(256) void gemm1_fused_kernel(
    const uint* __restrict__ xbf, const int* __restrict__ rowptr,
    const int* __restrict__ nbr, const float* __restrict__ W1,
    const float* __restrict__ b1, unsigned short* __restrict__ h16,
    float* __restrict__ stats) {
    __shared__ float sA[64][68];                 // +4 pad: 2-way bank alias (free)
    __shared__ unsigned short sWh[64][64];
    int tid = threadIdx.x;
    int row0 = blockIdx.x * 64;

    for (int i = tid; i < 1024; i += 256) {
        float4 w = reinterpret_cast<const float4*>(W1)[i];
        unsigned short* p = &sWh[0][0] + i * 4;
        p[0] = bf1(w.x); p[1] = bf1(w.y); p[2] = bf1(w.z); p[3] = bf1(w.w);
    }

    const uint4* xb4 = reinterpret_cast<const uint4*>(xbf);
    int c8 = tid & 7;        // uint4 slot within row (8 bf16 cols)
    int rslot = tid >> 3;    // 32 rows per pass
    for (int rr = 0; rr < 2; ++rr) {
        int r = rslot + 32 * rr;
        int gr = row0 + r;
        float a0 = 0.f, a1 = 0.f, a2 = 0.f, a3 = 0.f;
        float a4 = 0.f, a5 = 0.f, a6 = 0.f, a7 = 0.f;
        if (gr < N_NODES) {
            uint4 sv = xb4[(size_t)gr * 8 + c8];
            a0 = lo16(sv.x); a1 = hi16(sv.x); a2 = lo16(sv.y); a3 = hi16(sv.y);
            a4 = lo16(sv.z); a5 = hi16(sv.z); a6 = lo16(sv.w); a7 = hi16(sv.w);
            int beg = rowptr[gr], end = rowptr[gr + 1];
            int4 ia = *reinterpret_cast<const int4*>(nbr + beg);
            int4 ib = *reinterpret_cast<const int4*>(nbr + beg + 4);
            for (int j = beg; j < end; j += 8) {
                // prefetch next iteration's indices (may over-read <=64B; padded)
                int4 ian = *reinterpret_cast<const int4*>(nbr + j + 8);
                int4 ibn = *reinterpret_cast<const int4*>(nbr + j + 12);
                uint4 v0 = xb4[(size_t)ia.x * 8 + c8];
                uint4 v1 = xb4[(size_t)ia.y * 8 + c8];
                uint4 v2 = xb4[(size_t)ia.z * 8 + c8];
                uint4 v3 = xb4[(size_t)ia.w * 8 + c8];
                uint4 v4 = xb4[(size_t)ib.x * 8 + c8];
                uint4 v5 = xb4[(size_t)ib.y * 8 + c8];
                uint4 v6 = xb4[(size_t)ib.z * 8 + c8];
                uint4 v7 = xb4[(size_t)ib.w * 8 + c8];
                a0 += lo16(v0.x); a1 += hi16(v0.x); a2 += lo16(v0.y); a3 += hi16(v0.y);
                a4 += lo16(v0.z); a5 += hi16(v0.z); a6 += lo16(v0.w); a7 += hi16(v0.w);
                a0 += lo16(v1.x); a1 += hi16(v1.x); a2 += lo16(v1.y); a3 += hi16(v1.y);
                a4 += lo16(v1.z); a5 += hi16(v1.z); a6 += lo16(v1.w); a7 += hi16(v1.w);
                a0 += lo16(v2.x); a1 += hi16(v2.x); a2 += lo16(v2.y); a3 += hi16(v2.y);
                a4 += lo16(v2.z); a5 += hi16(v2.z); a6 += lo16(v2.w); a7 += hi16(v2.w);
                a0 += lo16(v3.x); a1 += hi16(v3.x); a2 += lo16(v3.y); a3 += hi16(v3.y);
                a4 += lo16(v3.z); a5 += hi16(v3.z); a6 += lo16(v3.w); a7 += hi16(v3.w);
                a0 += lo16(v4.x); a1 += hi16(v4.x); a2 += lo16(v4.y); a3 += hi16(v4.y);
                a4 += lo16(v4.z); a5 += hi16(v4.z); a6 += lo16(v4.w); a7 += hi16(v4.w);
                a0 += lo16(v5.x); a1 += hi16(v5.x); a2 += lo16(v5.y); a3 += hi16(v5.y);
                a4 += lo16(v5.z); a5 += hi16(v5.z); a6 += lo16(v5.w); a7 += hi16(v5.w);
                a0 += lo16(v6.x); a1 += hi16(v6.x); a2 += lo16(v6.y); a3 += hi16(v6.y);
                a4 += lo16(v6.z); a5 += hi16(v6.z); a6 += lo16(v6.w); a7 += hi16(v6.w);
                a0 += lo16(v7.x); a1 += hi16(v7.x); a2 += lo16(v7.y); a3 += hi16(v7.y);
                a4 += lo16(v7.z); a5 += hi16(v7.z); a6 += lo16(v7.w); a7 += hi16(v7.w);
                ia = ian; ib = ibn;
            }
        }
        *reinterpret_cast<float4*>(&sA[r][c8 * 8])     = make_float4(a0, a1, a2, a3);
        *reinterpret_cast<float4*>(&sA[r][c8 * 8 + 4]) = make_float4(a4, a5, a6, a7);
    }
    __syncthreads();

    // 4x4 register-tiled GEMM: thread (rt=tid>>4, ct=tid&15)
    int ct = tid & 15, rt = tid >> 4;
    int cbase = ct * 4, rbase = rt * 4;
    float4 bias = reinterpret_cast<const float4*>(b1)[ct];
    float acc[4][4];
    #pragma unroll
    for (int i = 0; i < 4; ++i) {
        acc[i][0] = bias.x; acc[i][1] = bias.y; acc[i][2] = bias.z; acc[i][3] = bias.w;
    }
    for (int k = 0; k < 64; ++k) {
        float A0 = sA[rbase + 0][k], A1 = sA[rbase + 1][k];
        float A2 = sA[rbase + 2][k], A3 = sA[rbase + 3][k];
        uint2 wp = *reinterpret_cast<const uint2*>(&sWh[k][cbase]);
        float w0 = lo16(wp.x), w1 = hi16(wp.x), w2 = lo16(wp.y), w3 = hi16(wp.y);
        acc[0][0] = fmaf(A0, w0, acc[0][0]); acc[0][1] = fmaf(A0, w1, acc[0][1]);
        acc[0][2] = fmaf(A0, w2, acc[0][2]); acc[0][3] = fmaf(A0, w3, acc[0][3]);
        acc[1][0] = fmaf(A1, w0, acc[1][0]); acc[1][1] = fmaf(A1, w1, acc[1][1]);
        acc[1][2] = fmaf(A1, w2, acc[1][2]); acc[1][3] = fmaf(A1, w3, acc[1][3]);
        acc[2][0] = fmaf(A2, w0, acc[2][0]); acc[2][1] = fmaf(A2, w1, acc[2][1]);
        acc[2][2] = fmaf(A2, w2, acc[2][2]); acc[2][3] = fmaf(A2, w3, acc[2][3]);
        acc[3][0] = fmaf(A3, w0, acc[3][0]); acc[3][1] = fmaf(A3, w1, acc[3][1]);
        acc[3][2] = fmaf(A3, w2, acc[3][2]); acc[3][3] = fmaf(A3, w3, acc[3][3]);
    }

    float csum[4] = {0.f, 0.f, 0.f, 0.f};
    float csq[4]  = {0.f, 0.f, 0.f, 0.f};
    #pragma unroll
    for (int i = 0; i < 4; ++i) {
        int gr = row0 + rbase + i;
        if (gr < N_NODES) {
            uint2 o;
            o.x = bf_pack(acc[i][0], acc[i][1]);
            o.y = bf_pack(acc[i][2], acc[i][3]);
            *reinterpret_cast<uint2*>(&h16[(size_t)gr * 64 + cbase]) = o;
            #pragma unroll
            for (int j = 0; j < 4; ++j) {
                csum[j] += acc[i][j];
                csq[j]  += acc[i][j] * acc[i][j];
            }
        }
    }
    __syncthreads();                     // sA reads done; reuse as scratch
    float* scratch = &sA[0][0];
    #pragma unroll
    for (int j = 0; j < 4; ++j) {
        scratch[rt * 136 + cbase + j]      = csum[j];
        scratch[rt * 136 + 64 + cbase + j] = csq[j];
    }
    __syncthreads();
    if (tid < 64) {
        float s = 0.f, q = 0.f;
        #pragma unroll
        for (int r2 = 0; r2 < 16; ++r2) {
            s += scratch[r2 * 136 + tid];
            q += scratch[r2 * 136 + 64 + tid];
        }
        unsafeAtomicAdd(&stats[tid], s);
        unsafeAtomicAdd(&stats[64 + tid], q);
    }
}

// -- GEMM2(4x4 tile) + pool: xn=relu(bn(h))@W2+b2; pooled += xn; xn->bf16 --
__global__ __launch_bounds__(256) void gemm2_pool_kernel(
    const unsigned short* __restrict__ h16, const float* __restrict__ stats,
    const float* __restrict__ gamma, const float* __restrict__ beta,
    const float* __restrict__ W2, const float* __restrict__ b2,
    const int* __restrict__ batch, float* __restrict__ pooled,
    unsigned short* __restrict__ xout) {
    __shared__ float sA[64][68];
    __shared__ unsigned short sWh[64][64];
    int tid = threadIdx.x;
    int row0 = blockIdx.x * 64;

    for (int i = tid; i < 1024; i += 256) {
        float4 w = reinterpret_cast<const float4*>(W2)[i];
        unsigned short* p = &sWh[0][0] + i * 4;
        p[0] = bf1(w.x); p[1] = bf1(w.y); p[2] = bf1(w.z); p[3] = bf1(w.w);
    }

    // per-thread BN scale/shift for its fixed 8 staging columns
    int c8 = tid & 7;
    float scv[8], shv[8];
    #pragma unroll
    for (int k = 0; k < 8; ++k) {
        int col = c8 * 8 + k;
        float mu = stats[col] * (1.0f / N_NODES);
        float var = stats[64 + col] * (1.0f / N_NODES) - mu * mu;
        scv[k] = gamma[col] * rsqrtf(var + BN_EPS);
        shv[k] = beta[col] - mu * scv[k];
    }

    const uint4* h4 = reinterpret_cast<const uint4*>(h16);
    for (int i = tid; i < 512; i += 256) {
        int r = i >> 3;                    // (i&7) == c8 since 256 % 8 == 0
        int gr = row0 + r;
        float o[8] = {0.f, 0.f, 0.f, 0.f, 0.f, 0.f, 0.f, 0.f};
        if (gr < N_NODES) {
            uint4 v = h4[(size_t)gr * 8 + c8];
            float f[8] = {lo16(v.x), hi16(v.x), lo16(v.y), hi16(v.y),
                          lo16(v.z), hi16(v.z), lo16(v.w), hi16(v.w)};
            #pragma unroll
            for (int k = 0; k < 8; ++k)
                o[k] = fmaxf(fmaf(f[k], scv[k], shv[k]), 0.f);
        }
        *reinterpret_cast<float4*>(&sA[r][c8 * 8]) = make_float4(o[0], o[1], o[2], o[3]);
        *reinterpret_cast<float4*>(&sA[r][c8 * 8 + 4]) = make_float4(o[4], o[5], o[6], o[7]);
    }
    __syncthreads();

    int ct = tid & 15, rt = tid >> 4;
    int cbase = ct * 4, rbase = rt * 4;
    float4 bias = reinterpret_cast<const float4*>(b2)[ct];
    float acc[4][4];
    #pragma unroll
    for (int i = 0; i < 4; ++i) {
        acc[i][0] = bias.x; acc[i][1] = bias.y; acc[i][2] = bias.z; acc[i][3] = bias.w;
    }
    for (int k = 0; k < 64; ++k) {
        float A0 = sA[rbase + 0][k], A1 = sA[rbase + 1][k];
        float A2 = sA[rbase + 2][k], A3 = sA[rbase + 3][k];
        uint2 wp = *reinterpret_cast<const uint2*>(&sWh[k][cbase]);
        float w0 = lo16(wp.x), w1 = hi16(wp.x), w2 = lo16(wp.y), w3 = hi16(wp.y);
        acc[0][0] = fmaf(A0, w0, acc[0][0]); acc[0][1] = fmaf(A0, w1, acc[0][1]);
        acc[0][2] = fmaf(A0, w2, acc[0][2]); acc[0][3] = fmaf(A0, w3, acc[0][3]);
        acc[1][0] = fmaf(A1, w0, acc[1][0]); acc[1][1] = fmaf(A1, w1, acc[1][1]);
        acc[1][2] = fmaf(A1, w2, acc[1][2]); acc[1][3] = fmaf(A1, w3, acc[1][3]);
        acc[2][0] = fmaf(A2, w0, acc[2][0]); acc[2][1] = fmaf(A2, w1, acc[2][1]);
        acc[2][2] = fmaf(A2, w2, acc[2][2]); acc[2][3] = fmaf(A2, w3, acc[2][3]);
        acc[3][0] = fmaf(A3, w0, acc[3][0]); acc[3][1] = fmaf(A3, w1, acc[3][1]);
        acc[3][2] = fmaf(A3, w2, acc[3][2]); acc[3][3] = fmaf(A3, w3, acc[3][3]);
    }

    // write xout (bf16)
    #pragma unroll
    for (int i = 0; i < 4; ++i) {
        int gr = row0 + rbase + i;
        if (gr < N_NODES) {
            uint2 o;
            o.x = bf_pack(acc[i][0], acc[i][1]);
            o.y = bf_pack(acc[i][2], acc[i][3]);
            *reinterpret_cast<uint2*>(&xout[(size_t)gr * 64 + cbase]) = o;
        }
    }

    // pool: single-graph block -> LDS reduce + 1 atomic/col; else run-length
    int lastrow = row0 + 63; if (lastrow >= N_NODES) lastrow = N_NODES - 1;
    int b0 = batch[row0], bL = batch[lastrow];
    if (b0 == bL) {
        float psum[4] = {0.f, 0.f, 0.f, 0.f};
        #pragma unroll
        for (int i = 0; i < 4; ++i) {
            int gr = row0 + rbase + i;
            if (gr < N_NODES) {
                #pragma unroll
                for (int j = 0; j < 4; ++j) psum[j] += acc[i][j];
            }
        }
        __syncthreads();                 // sA reads done; reuse as scratch
        float* scratch = &sA[0][0];
        #pragma unroll
        for (int j = 0; j < 4; ++j) scratch[rt * 68 + cbase + j] = psum[j];
        __syncthreads();
        if (tid < 64) {
            float s = 0.f;
            #pragma unroll
            for (int r2 = 0; r2 < 16; ++r2) s += scratch[r2 * 68 + tid];
            unsafeAtomicAdd(&pooled[b0 * 64 + tid], s);
        }
    } else {
        #pragma unroll
        for (int j = 0; j < 4; ++j) {
            float pacc = 0.f;
            int curb = -1;
            #pragma unroll
            for (int i = 0; i < 4; ++i) {
                int gr = row0 + rbase + i;
                if (gr < N_NODES) {
                    int b = batch[gr];
                    if (b != curb) {
                        if (curb >= 0) unsafeAtomicAdd(&pooled[curb * 64 + cbase + j], pacc);
                        curb = b;
                        pacc = 0.f;
                    }
                    pacc += acc[i][j];
                }
            }
            if (curb >= 0) unsafeAtomicAdd(&pooled[curb * 64 + cbase + j], pacc);
        }
    }
}

// -------------------- output: score += pooled @ Wout + bout --------------
__global__ void out_kernel(const float* __restrict__ pooled,
                           const float* __restrict__ Wout,
                           const float* __restrict__ bout,
                           float* __restrict__ score) {
    int idx = blockIdx.x * blockDim.x + threadIdx.x;
    if (idx >= G_GRAPHS * OUT_F) return;
    int g = idx / OUT_F;
    int o = idx - g * OUT_F;
    float acc = bout[o];
    #pragma unroll
    for (int k = 0; k < 64; ++k) acc += pooled[g * 64 + k] * Wout[k * OUT_F + o];
    score[idx] += acc;
}

extern "C" void kernel_launch(void* const* d_in, const int* in_sizes, int n_in,
                              void* d_out, int out_size, void* d_ws, size_t ws_size,
                              hipStream_t stream) {
    const float* x     = (const float*)d_in[0];
    const int*   ei    = (const int*)d_in[1];
    const int*   batch = (const int*)d_in[2];
    const float* W1    = (const float*)d_in[3];
    const float* b1    = (const float*)d_in[4];
    const float* gamma = (const float*)d_in[5];
    const float* beta  = (const float*)d_in[6];
    const float* W2    = (const float*)d_in[7];
    const float* b2    = (const float*)d_in[8];
    const float* Wout  = (const float*)d_in[9];
    const float* bout  = (const float*)d_in[10];
    float* out = (float*)d_out;

    unsigned short* H16 = (unsigned short*)d_ws;             // N*64 bf16
    uint*  XBF    = (uint*)(H16 + (size_t)N_NODES * 64);     // (N+1)*32 uints
    float* stats  = (float*)(XBF + (size_t)(N_NODES + 1) * 32);  // 128
    float* pooled = stats + 128;                             // G*64 (adjacent)
    int*   deg    = (int*)(pooled + (size_t)G_GRAPHS * 64);  // N
    int*   rowptr = deg + N_NODES;                           // N+4
    int*   cursor = rowptr + N_NODES + 4;                    // N
    int*   bsum   = cursor + N_NODES;                        // SCAN_BLOCKS (pad 120)
    int*   gcur   = bsum + 120;                              // 8
    int*   nbr    = gcur + 8;                                // E + 8N + 16 (padded CSR)
    int2*  epair  = (int2*)(nbr + E_EDGES + 8 * N_NODES + 16);  // 8*BCAP pairs

    const int* src = ei;
    const int* dst = ei + E_EDGES;

    (void)hipMemsetAsync(d_out, 0, (size_t)G_GRAPHS * OUT_F * sizeof(float), stream);
    (void)hipMemsetAsync(deg, 0, (size_t)N_NODES * sizeof(int), stream);

    deg_kernel<<<(E_EDGES / 4 + 255) / 256, 256, 0, stream>>>(dst, deg);
    scanA_kernel<<<SCAN_BLOCKS, 256, 0, stream>>>(deg, bsum);
    scanB_kernel<<<1, 128, 0, stream>>>(bsum, rowptr, gcur);
    scanC_kernel<<<SCAN_BLOCKS, 256, 0, stream>>>(deg, bsum, rowptr, cursor);
    fillA_kernel<<<NCHUNK, 256, 0, stream>>>(src, dst, gcur, epair);
    fillB_kernel<<<FB_GRID, 256, 0, stream>>>(epair, gcur, cursor, nbr);
    pad_kernel<<<(N_NODES + 255) / 256, 256, 0, stream>>>(rowptr, deg, nbr);
    tobf_kernel<<<(N_NODES * 8 + 255) / 256, 256, 0, stream>>>(x, XBF);

    int nb = (N_NODES + 63) / 64;

    for (int l = 0; l < L_LAYERS; ++l) {
        // stats (128) + pooled (G*64) are adjacent: one memset
        (void)hipMemsetAsync(stats, 0, (128 + (size_t)G_GRAPHS * 64) * sizeof(float), stream);

        gemm1_fused_kernel<<<nb, 256, 0, stream>>>(XBF, rowptr, nbr,
            W1 + l * 64 * 64, b1 + l * 64, H16, stats);
        gemm2_pool_kernel<<<nb, 256, 0, stream>>>(H16, stats,
            gamma + l * 64, beta + l * 64, W2 + l * 64 * 64, b2 + l * 64, batch,
            pooled, (unsigned short*)XBF);
        out_kernel<<<(G_GRAPHS * OUT_F + 127) / 128, 128, 0, stream>>>(
            pooled, Wout + l * 64 * OUT_F, bout + l * OUT_F, out);
    }
}

// Round 14
// 425.627 us; speedup vs baseline: 1.2364x; 1.0891x over previous
//
#include <hip/hip_runtime.h>

typedef unsigned int uint;
typedef int iv4 __attribute__((ext_vector_type(4)));

#define N_NODES 100000
#define E_EDGES 1600000
#define L_LAYERS 3
#define G_GRAPHS 128
#define OUT_F 10
#define BN_EPS 1e-5f

#define NB4 (N_NODES / 4)                 // 25000 int4 chunks
#define SCAN_BLOCKS ((NB4 + 255) / 256)   // 98
#define BSHIFT 7                          // 128-node stripes
#define NSTRIPE ((N_NODES + 127) >> 7)    // 782
#define CHUNK 2048
#define NCHUNK ((E_EDGES + CHUNK - 1) / CHUNK)   // 782
#define PAD8(d) (((d) + 7) & ~7)
#define BCAP (2048 * 103)                 // per-XCD queue capacity (pairs)
#define FB_GRID (103 * 8)
#define SCAP 2560                         // per-stripe queue capacity (pairs; 11 sd slack)

// bf16 pack (RTNE) / unpack helpers
__device__ __forceinline__ uint bf_pack(float a, float b) {
    uint ua = __float_as_uint(a);
    ua = (ua + 0x7fffu + ((ua >> 16) & 1u)) >> 16;
    uint ub = __float_as_uint(b);
    ub = (ub + 0x7fffu + ((ub >> 16) & 1u)) >> 16;
    return ua | (ub << 16);
}
__device__ __forceinline__ unsigned short bf1(float a) {
    uint ua = __float_as_uint(a);
    return (unsigned short)((ua + 0x7fffu + ((ua >> 16) & 1u)) >> 16);
}
__device__ __forceinline__ float lo16(uint u) { return __uint_as_float(u << 16); }
__device__ __forceinline__ float hi16(uint u) { return __uint_as_float(u & 0xffff0000u); }

// -------------------- CSR build: degree histogram (int4, nt loads) -------
__global__ __launch_bounds__(256) void deg_kernel(const int* __restrict__ dst,
                                                  int* __restrict__ deg) {
    int i = blockIdx.x * blockDim.x + threadIdx.x;   // E/4 threads
    if (i < E_EDGES / 4) {
        iv4 d = __builtin_nontemporal_load(reinterpret_cast<const iv4*>(dst) + i);
        atomicAdd(&deg[d.x], 1);
        atomicAdd(&deg[d.y], 1);
        atomicAdd(&deg[d.z], 1);
        atomicAdd(&deg[d.w], 1);
    }
}

// -------------------- scan phase A: per-block sums (padded degrees) ------
__global__ __launch_bounds__(256) void scanA_kernel(const int* __restrict__ deg,
                                                    int* __restrict__ bsum) {
    __shared__ int red[256];
    int t = threadIdx.x;
    int i4 = blockIdx.x * 256 + t;
    int s = 0;
    if (i4 < NB4) {
        int4 v = reinterpret_cast<const int4*>(deg)[i4];
        s = PAD8(v.x) + PAD8(v.y) + PAD8(v.z) + PAD8(v.w);
    }
    red[t] = s;
    __syncthreads();
    for (int off = 128; off > 0; off >>= 1) {
        if (t < off) red[t] += red[t + off];
        __syncthreads();
    }
    if (t == 0) bsum[blockIdx.x] = red[0];
}

// ------------- scan phase B: scan block sums; init XCD queue bases -------
__global__ __launch_bounds__(128) void scanB_kernel(int* __restrict__ bsum,
                                                    int* __restrict__ rowptr,
                                                    int* __restrict__ gcur) {
    __shared__ int p[128];
    int t = threadIdx.x;
    int v = (t < SCAN_BLOCKS) ? bsum[t] : 0;
    p[t] = v;
    __syncthreads();
    for (int off = 1; off < 128; off <<= 1) {
        int u = (t >= off) ? p[t - off] : 0;
        __syncthreads();
        p[t] += u;
        __syncthreads();
    }
    if (t < SCAN_BLOCKS) bsum[t] = p[t] - v;      // exclusive block offset
    if (t == 127) rowptr[N_NODES] = p[127];       // total (padded)
    if (t < 8) gcur[t] = t * BCAP;                // per-XCD queue bases
}

// --- scan phase C: write padded rowptr; init per-stripe queue bases ------
__global__ __launch_bounds__(256) void scanC_kernel(
    const int* __restrict__ deg, const int* __restrict__ bsum,
    int* __restrict__ rowptr, int* __restrict__ scur) {
    __shared__ int ts[256];
    int t = threadIdx.x;
    int gid = blockIdx.x * 256 + t;
    if (gid < NSTRIPE) scur[gid] = gid * SCAP;    // stripe queue bases
    int i4 = gid;
    int4 v = make_int4(0, 0, 0, 0);
    if (i4 < NB4) v = reinterpret_cast<const int4*>(deg)[i4];
    int4 pv = make_int4(PAD8(v.x), PAD8(v.y), PAD8(v.z), PAD8(v.w));
    int s = pv.x + pv.y + pv.z + pv.w;
    ts[t] = s;
    __syncthreads();
    for (int off = 1; off < 256; off <<= 1) {
        int u = (t >= off) ? ts[t - off] : 0;
        __syncthreads();
        ts[t] += u;
        __syncthreads();
    }
    if (i4 < NB4) {
        int base = bsum[blockIdx.x] + ts[t] - s;   // exclusive prefix
        int4 rp;
        rp.x = base;
        rp.y = rp.x + pv.x;
        rp.z = rp.y + pv.y;
        rp.w = rp.z + pv.z;
        reinterpret_cast<int4*>(rowptr)[i4] = rp;
    }
}

// ---- fill pass A: bin edges into 8 per-XCD queues (single read of ei) ----
__global__ __launch_bounds__(256) void fillA_kernel(
    const int* __restrict__ src, const int* __restrict__ dst,
    int* __restrict__ gcur, int2* __restrict__ epair) {
    __shared__ int lcnt[8];
    __shared__ int lbase[8];
    int tid = threadIdx.x;
    int base = blockIdx.x * CHUNK;
    if (tid < 8) lcnt[tid] = 0;
    __syncthreads();

    int sd[8], ss[8], bk[8], off[8];
    #pragma unroll
    for (int it = 0; it < 8; ++it) {
        int e = base + it * 256 + tid;
        bk[it] = -1;
        if (e < E_EDGES) {
            sd[it] = dst[e];
            ss[it] = src[e];
            bk[it] = (sd[it] >> BSHIFT) & 7;
            off[it] = atomicAdd(&lcnt[bk[it]], 1);
        }
    }
    __syncthreads();
    if (tid < 8) lbase[tid] = atomicAdd(&gcur[tid], lcnt[tid]);
    __syncthreads();
    #pragma unroll
    for (int it = 0; it < 8; ++it) {
        if (bk[it] >= 0)
            epair[lbase[bk[it]] + off[it]] = make_int2(ss[it], sd[it]);
    }
}

// ---- fill pass B2: bin XCD queue by stripe (98 buckets per XCD) ----------
// stripe s = d>>7 (s&7 == g); bucket k = d>>10; queue written AND read only
// by XCD g -> stripe queues stay L2-resident.
__global__ __launch_bounds__(256) void fillB2_kernel(
    const int2* __restrict__ epair1, const int* __restrict__ gcur,
    int* __restrict__ scur, int2* __restrict__ epair2) {
    __shared__ int lcnt[98];
    __shared__ int lbase[98];
    int tid = threadIdx.x;
    int g = blockIdx.x & 7;
    int c = blockIdx.x >> 3;
    int ebeg = g * BCAP + c * CHUNK;
    int eend = gcur[g];
    if (tid < 98) lcnt[tid] = 0;
    __syncthreads();

    int2 pp[8]; int bk[8], off[8];
    #pragma unroll
    for (int it = 0; it < 8; ++it) {
        int i = ebeg + it * 256 + tid;
        bk[it] = -1;
        if (i < eend) {
            pp[it] = epair1[i];
            bk[it] = pp[it].y >> 10;               // fine bucket within XCD
            off[it] = atomicAdd(&lcnt[bk[it]], 1);
        }
    }
    __syncthreads();
    if (tid < 98 && lcnt[tid] > 0)
        lbase[tid] = atomicAdd(&scur[(tid << 3) | g], lcnt[tid]);
    __syncthreads();
    #pragma unroll
    for (int it = 0; it < 8; ++it) {
        if (bk[it] >= 0)
            epair2[lbase[bk[it]] + off[it]] = pp[it];
    }
}

// ---- fill pass C: per-stripe LDS counting-place + sequential nbr write ---
// offsets come from rowptr/deg (no cursors); sentinels from buffer init;
// output written coalesced as int4 -> zero write amplification.
__global__ __launch_bounds__(256) void fillC_kernel(
    const int2* __restrict__ epair2, const int* __restrict__ scur,
    const int* __restrict__ rowptr, int* __restrict__ nbr) {
    __shared__ int off[128];
    __shared__ int buf[4096];
    int s = blockIdx.x;                    // stripe
    int tid = threadIdx.x;
    int node0 = s << 7;
    int base0 = rowptr[node0];
    int nlim = node0 + 128 <= N_NODES ? node0 + 128 : N_NODES;
    int total = rowptr[nlim] - base0;      // padded stripe size (mult of 8)

    for (int i = tid; i < 4096; i += 256) buf[i] = N_NODES;   // sentinel
    if (tid < 128) {
        int nd = node0 + tid;
        off[tid] = (nd < nlim ? rowptr[nd] : rowptr[nlim]) - base0;
    }
    __syncthreads();

    int qbeg = s * SCAP;
    int qend = scur[s];                    // base + count after fillB2
    for (int i = qbeg + tid; i < qend; i += 256) {
        int2 p = epair2[i];
        int dl = p.y & 127;
        int pos = atomicAdd(&off[dl], 1);
        buf[pos] = p.x;
    }
    __syncthreads();

    for (int i = tid * 4; i < total; i += 1024)
        *reinterpret_cast<int4*>(nbr + base0 + i) = *reinterpret_cast<const int4*>(buf + i);
}

// -------------------- x f32 -> bf16 (layer 0 only) ------------------------
__global__ __launch_bounds__(256) void tobf_kernel(const float* __restrict__ x,
                                                   uint* __restrict__ xbf) {
    int i = blockIdx.x * 256 + threadIdx.x;   // N*8 threads, 8 floats each
    if (i < N_NODES * 8) {
        float4 a = reinterpret_cast<const float4*>(x)[i * 2];
        float4 b = reinterpret_cast<const float4*>(x)[i * 2 + 1];
        uint4 o;
        o.x = bf_pack(a.x, a.y);
        o.y = bf_pack(a.z, a.w);
        o.z = bf_pack(b.x, b.y);
        o.w = bf_pack(b.z, b.w);
        reinterpret_cast<uint4*>(xbf)[i] = o;
    }
    if (i < 8) reinterpret_cast<uint4*>(xbf)[N_NODES * 8 + i] = make_uint4(0, 0, 0, 0);
}

// ------- fused gather(bf16, padded CSR, idx-prefetch) + GEMM1 + stats -----
__global__ __launch_bounds__(256) void gemm1_fused_kernel(
    const uint* __restrict__ xbf, const int* __restrict__ rowptr,
    const int* __restrict__ nbr, const float* __restrict__ W1,
    const float* __restrict__ b1, unsigned short* __restrict__ h16,
    float* __restrict__ stats) {
    __shared__ float sA[64][68];                 // +4 pad: 2-way bank alias (free)
    __shared__ unsigned short sWh[64][64];
    int tid = threadIdx.x;
    int row0 = blockIdx.x * 64;

    for (int i = tid; i < 1024; i += 256) {
        float4 w = reinterpret_cast<const float4*>(W1)[i];
        unsigned short* p = &sWh[0][0] + i * 4;
        p[0] = bf1(w.x); p[1] = bf1(w.y); p[2] = bf1(w.z); p[3] = bf1(w.w);
    }

    const uint4* xb4 = reinterpret_cast<const uint4*>(xbf);
    int c8 = tid & 7;        // uint4 slot within row (8 bf16 cols)
    int rslot = tid >> 3;    // 32 rows per pass
    for (int rr = 0; rr < 2; ++rr) {
        int r = rslot + 32 * rr;
        int gr = row0 + r;
        float a0 = 0.f, a1 = 0.f, a2 = 0.f, a3 = 0.f;
        float a4 = 0.f, a5 = 0.f, a6 = 0.f, a7 = 0.f;
        if (gr < N_NODES) {
            uint4 sv = xb4[(size_t)gr * 8 + c8];
            a0 = lo16(sv.x); a1 = hi16(sv.x); a2 = lo16(sv.y); a3 = hi16(sv.y);
            a4 = lo16(sv.z); a5 = hi16(sv.z); a6 = lo16(sv.w); a7 = hi16(sv.w);
            int beg = rowptr[gr], end = rowptr[gr + 1];
            int4 ia = *reinterpret_cast<const int4*>(nbr + beg);
            int4 ib = *reinterpret_cast<const int4*>(nbr + beg + 4);
            for (int j = beg; j < end; j += 8) {
                int4 ian = *reinterpret_cast<const int4*>(nbr + j + 8);
                int4 ibn = *reinterpret_cast<const int4*>(nbr + j + 12);
                uint4 v0 = xb4[(size_t)ia.x * 8 + c8];
                uint4 v1 = xb4[(size_t)ia.y * 8 + c8];
                uint4 v2 = xb4[(size_t)ia.z * 8 + c8];
                uint4 v3 = xb4[(size_t)ia.w * 8 + c8];
                uint4 v4 = xb4[(size_t)ib.x * 8 + c8];
                uint4 v5 = xb4[(size_t)ib.y * 8 + c8];
                uint4 v6 = xb4[(size_t)ib.z * 8 + c8];
                uint4 v7 = xb4[(size_t)ib.w * 8 + c8];
                a0 += lo16(v0.x); a1 += hi16(v0.x); a2 += lo16(v0.y); a3 += hi16(v0.y);
                a4 += lo16(v0.z); a5 += hi16(v0.z); a6 += lo16(v0.w); a7 += hi16(v0.w);
                a0 += lo16(v1.x); a1 += hi16(v1.x); a2 += lo16(v1.y); a3 += hi16(v1.y);
                a4 += lo16(v1.z); a5 += hi16(v1.z); a6 += lo16(v1.w); a7 += hi16(v1.w);
                a0 += lo16(v2.x); a1 += hi16(v2.x); a2 += lo16(v2.y); a3 += hi16(v2.y);
                a4 += lo16(v2.z); a5 += hi16(v2.z); a6 += lo16(v2.w); a7 += hi16(v2.w);
                a0 += lo16(v3.x); a1 += hi16(v3.x); a2 += lo16(v3.y); a3 += hi16(v3.y);
                a4 += lo16(v3.z); a5 += hi16(v3.z); a6 += lo16(v3.w); a7 += hi16(v3.w);
                a0 += lo16(v4.x); a1 += hi16(v4.x); a2 += lo16(v4.y); a3 += hi16(v4.y);
                a4 += lo16(v4.z); a5 += hi16(v4.z); a6 += lo16(v4.w); a7 += hi16(v4.w);
                a0 += lo16(v5.x); a1 += hi16(v5.x); a2 += lo16(v5.y); a3 += hi16(v5.y);
                a4 += lo16(v5.z); a5 += hi16(v5.z); a6 += lo16(v5.w); a7 += hi16(v5.w);
                a0 += lo16(v6.x); a1 += hi16(v6.x); a2 += lo16(v6.y); a3 += hi16(v6.y);
                a4 += lo16(v6.z); a5 += hi16(v6.z); a6 += lo16(v6.w); a7 += hi16(v6.w);
                a0 += lo16(v7.x); a1 += hi16(v7.x); a2 += lo16(v7.y); a3 += hi16(v7.y);
                a4 += lo16(v7.z); a5 += hi16(v7.z); a6 += lo16(v7.w); a7 += hi16(v7.w);
                ia = ian; ib = ibn;
            }
        }
        *reinterpret_cast<float4*>(&sA[r][c8 * 8])     = make_float4(a0, a1, a2, a3);
        *reinterpret_cast<float4*>(&sA[r][c8 * 8 + 4]) = make_float4(a4, a5, a6, a7);
    }
    __syncthreads();

    // 4x4 register-tiled GEMM: thread (rt=tid>>4, ct=tid&15)
    int ct = tid & 15, rt = tid >> 4;
    int cbase = ct * 4, rbase = rt * 4;
    float4 bias = reinterpret_cast<const float4*>(b1)[ct];
    float acc[4][4];
    #pragma unroll
    for (int i = 0; i < 4; ++i) {
        acc[i][0] = bias.x; acc[i][1] = bias.y; acc[i][2] = bias.z; acc[i][3] = bias.w;
    }
    for (int k = 0; k < 64; ++k) {
        float A0 = sA[rbase + 0][k], A1 = sA[rbase + 1][k];
        float A2 = sA[rbase + 2][k], A3 = sA[rbase + 3][k];
        uint2 wp = *reinterpret_cast<const uint2*>(&sWh[k][cbase]);
        float w0 = lo16(wp.x), w1 = hi16(wp.x), w2 = lo16(wp.y), w3 = hi16(wp.y);
        acc[0][0] = fmaf(A0, w0, acc[0][0]); acc[0][1] = fmaf(A0, w1, acc[0][1]);
        acc[0][2] = fmaf(A0, w2, acc[0][2]); acc[0][3] = fmaf(A0, w3, acc[0][3]);
        acc[1][0] = fmaf(A1, w0, acc[1][0]); acc[1][1] = fmaf(A1, w1, acc[1][1]);
        acc[1][2] = fmaf(A1, w2, acc[1][2]); acc[1][3] = fmaf(A1, w3, acc[1][3]);
        acc[2][0] = fmaf(A2, w0, acc[2][0]); acc[2][1] = fmaf(A2, w1, acc[2][1]);
        acc[2][2] = fmaf(A2, w2, acc[2][2]); acc[2][3] = fmaf(A2, w3, acc[2][3]);
        acc[3][0] = fmaf(A3, w0, acc[3][0]); acc[3][1] = fmaf(A3, w1, acc[3][1]);
        acc[3][2] = fmaf(A3, w2, acc[3][2]); acc[3][3] = fmaf(A3, w3, acc[3][3]);
    }

    float csum[4] = {0.f, 0.f, 0.f, 0.f};
    float csq[4]  = {0.f, 0.f, 0.f, 0.f};
    #pragma unroll
    for (int i = 0; i < 4; ++i) {
        int gr = row0 + rbase + i;
        if (gr < N_NODES) {
            uint2 o;
            o.x = bf_pack(acc[i][0], acc[i][1]);
            o.y = bf_pack(acc[i][2], acc[i][3]);
            *reinterpret_cast<uint2*>(&h16[(size_t)gr * 64 + cbase]) = o;
            #pragma unroll
            for (int j = 0; j < 4; ++j) {
                csum[j] += acc[i][j];
                csq[j]  += acc[i][j] * acc[i][j];
            }
        }
    }
    __syncthreads();                     // sA reads done; reuse as scratch
    float* scratch = &sA[0][0];
    #pragma unroll
    for (int j = 0; j < 4; ++j) {
        scratch[rt * 136 + cbase + j]      = csum[j];
        scratch[rt * 136 + 64 + cbase + j] = csq[j];
    }
    __syncthreads();
    if (tid < 64) {
        float s = 0.f, q = 0.f;
        #pragma unroll
        for (int r2 = 0; r2 < 16; ++r2) {
            s += scratch[r2 * 136 + tid];
            q += scratch[r2 * 136 + 64 + tid];
        }
        unsafeAtomicAdd(&stats[tid], s);
        unsafeAtomicAdd(&stats[64 + tid], q);
    }
}

// -- GEMM2(4x4 tile) + pool: xn=relu(bn(h))@W2+b2; pooled += xn; xn->bf16 --
__global__ __launch_bounds__(256) void gemm2_pool_kernel(
    const unsigned short* __restrict__ h16, const float* __restrict__ stats,
    const float* __restrict__ gamma, const float* __restrict__ beta,
    const float* __restrict__ W2, const float* __restrict__ b2,
    const int* __restrict__ batch, float* __restrict__ pooled,
    unsigned short* __restrict__ xout) {
    __shared__ float sA[64][68];
    __shared__ unsigned short sWh[64][64];
    int tid = threadIdx.x;
    int row0 = blockIdx.x * 64;

    for (int i = tid; i < 1024; i += 256) {
        float4 w = reinterpret_cast<const float4*>(W2)[i];
        unsigned short* p = &sWh[0][0] + i * 4;
        p[0] = bf1(w.x); p[1] = bf1(w.y); p[2] = bf1(w.z); p[3] = bf1(w.w);
    }

    // per-thread BN scale/shift for its fixed 8 staging columns
    int c8 = tid & 7;
    float scv[8], shv[8];
    #pragma unroll
    for (int k = 0; k < 8; ++k) {
        int col = c8 * 8 + k;
        float mu = stats[col] * (1.0f / N_NODES);
        float var = stats[64 + col] * (1.0f / N_NODES) - mu * mu;
        scv[k] = gamma[col] * rsqrtf(var + BN_EPS);
        shv[k] = beta[col] - mu * scv[k];
    }

    const uint4* h4 = reinterpret_cast<const uint4*>(h16);
    for (int i = tid; i < 512; i += 256) {
        int r = i >> 3;                    // (i&7) == c8 since 256 % 8 == 0
        int gr = row0 + r;
        float o[8] = {0.f, 0.f, 0.f, 0.f, 0.f, 0.f, 0.f, 0.f};
        if (gr < N_NODES) {
            uint4 v = h4[(size_t)gr * 8 + c8];
            float f[8] = {lo16(v.x), hi16(v.x), lo16(v.y), hi16(v.y),
                          lo16(v.z), hi16(v.z), lo16(v.w), hi16(v.w)};
            #pragma unroll
            for (int k = 0; k < 8; ++k)
                o[k] = fmaxf(fmaf(f[k], scv[k], shv[k]), 0.f);
        }
        *reinterpret_cast<float4*>(&sA[r][c8 * 8]) = make_float4(o[0], o[1], o[2], o[3]);
        *reinterpret_cast<float4*>(&sA[r][c8 * 8 + 4]) = make_float4(o[4], o[5], o[6], o[7]);
    }
    __syncthreads();

    int ct = tid & 15, rt = tid >> 4;
    int cbase = ct * 4, rbase = rt * 4;
    float4 bias = reinterpret_cast<const float4*>(b2)[ct];
    float acc[4][4];
    #pragma unroll
    for (int i = 0; i < 4; ++i) {
        acc[i][0] = bias.x; acc[i][1] = bias.y; acc[i][2] = bias.z; acc[i][3] = bias.w;
    }
    for (int k = 0; k < 64; ++k) {
        float A0 = sA[rbase + 0][k], A1 = sA[rbase + 1][k];
        float A2 = sA[rbase + 2][k], A3 = sA[rbase + 3][k];
        uint2 wp = *reinterpret_cast<const uint2*>(&sWh[k][cbase]);
        float w0 = lo16(wp.x), w1 = hi16(wp.x), w2 = lo16(wp.y), w3 = hi16(wp.y);
        acc[0][0] = fmaf(A0, w0, acc[0][0]); acc[0][1] = fmaf(A0, w1, acc[0][1]);
        acc[0][2] = fmaf(A0, w2, acc[0][2]); acc[0][3] = fmaf(A0, w3, acc[0][3]);
        acc[1][0] = fmaf(A1, w0, acc[1][0]); acc[1][1] = fmaf(A1, w1, acc[1][1]);
        acc[1][2] = fmaf(A1, w2, acc[1][2]); acc[1][3] = fmaf(A1, w3, acc[1][3]);
        acc[2][0] = fmaf(A2, w0, acc[2][0]); acc[2][1] = fmaf(A2, w1, acc[2][1]);
        acc[2][2] = fmaf(A2, w2, acc[2][2]); acc[2][3] = fmaf(A2, w3, acc[2][3]);
        acc[3][0] = fmaf(A3, w0, acc[3][0]); acc[3][1] = fmaf(A3, w1, acc[3][1]);
        acc[3][2] = fmaf(A3, w2, acc[3][2]); acc[3][3] = fmaf(A3, w3, acc[3][3]);
    }

    // write xout (bf16)
    #pragma unroll
    for (int i = 0; i < 4; ++i) {
        int gr = row0 + rbase + i;
        if (gr < N_NODES) {
            uint2 o;
            o.x = bf_pack(acc[i][0], acc[i][1]);
            o.y = bf_pack(acc[i][2], acc[i][3]);
            *reinterpret_cast<uint2*>(&xout[(size_t)gr * 64 + cbase]) = o;
        }
    }

    // pool: single-graph block -> LDS reduce + 1 atomic/col; else run-length
    int lastrow = row0 + 63; if (lastrow >= N_NODES) lastrow = N_NODES - 1;
    int b0 = batch[row0], bL = batch[lastrow];
    if (b0 == bL) {
        float psum[4] = {0.f, 0.f, 0.f, 0.f};
        #pragma unroll
        for (int i = 0; i < 4; ++i) {
            int gr = row0 + rbase + i;
            if (gr < N_NODES) {
                #pragma unroll
                for (int j = 0; j < 4; ++j) psum[j] += acc[i][j];
            }
        }
        __syncthreads();                 // sA reads done; reuse as scratch
        float* scratch = &sA[0][0];
        #pragma unroll
        for (int j = 0; j < 4; ++j) scratch[rt * 68 + cbase + j] = psum[j];
        __syncthreads();
        if (tid < 64) {
            float s = 0.f;
            #pragma unroll
            for (int r2 = 0; r2 < 16; ++r2) s += scratch[r2 * 68 + tid];
            unsafeAtomicAdd(&pooled[b0 * 64 + tid], s);
        }
    } else {
        #pragma unroll
        for (int j = 0; j < 4; ++j) {
            float pacc = 0.f;
            int curb = -1;
            #pragma unroll
            for (int i = 0; i < 4; ++i) {
                int gr = row0 + rbase + i;
                if (gr < N_NODES) {
                    int b = batch[gr];
                    if (b != curb) {
                        if (curb >= 0) unsafeAtomicAdd(&pooled[curb * 64 + cbase + j], pacc);
                        curb = b;
                        pacc = 0.f;
                    }
                    pacc += acc[i][j];
                }
            }
            if (curb >= 0) unsafeAtomicAdd(&pooled[curb * 64 + cbase + j], pacc);
        }
    }
}

// -------------------- output: score += pooled @ Wout + bout --------------
__global__ void out_kernel(const float* __restrict__ pooled,
                           const float* __restrict__ Wout,
                           const float* __restrict__ bout,
                           float* __restrict__ score) {
    int idx = blockIdx.x * blockDim.x + threadIdx.x;
    if (idx >= G_GRAPHS * OUT_F) return;
    int g = idx / OUT_F;
    int o = idx - g * OUT_F;
    float acc = bout[o];
    #pragma unroll
    for (int k = 0; k < 64; ++k) acc += pooled[g * 64 + k] * Wout[k * OUT_F + o];
    score[idx] += acc;
}

extern "C" void kernel_launch(void* const* d_in, const int* in_sizes, int n_in,
                              void* d_out, int out_size, void* d_ws, size_t ws_size,
                              hipStream_t stream) {
    const float* x     = (const float*)d_in[0];
    const int*   ei    = (const int*)d_in[1];
    const int*   batch = (const int*)d_in[2];
    const float* W1    = (const float*)d_in[3];
    const float* b1    = (const float*)d_in[4];
    const float* gamma = (const float*)d_in[5];
    const float* beta  = (const float*)d_in[6];
    const float* W2    = (const float*)d_in[7];
    const float* b2    = (const float*)d_in[8];
    const float* Wout  = (const float*)d_in[9];
    const float* bout  = (const float*)d_in[10];
    float* out = (float*)d_out;

    unsigned short* H16 = (unsigned short*)d_ws;             // N*64 bf16
    uint*  XBF    = (uint*)(H16 + (size_t)N_NODES * 64);     // (N+1)*32 uints
    float* stats  = (float*)(XBF + (size_t)(N_NODES + 1) * 32);  // 128
    float* pooled = stats + 128;                             // G*64 (adjacent)
    int*   deg    = (int*)(pooled + (size_t)G_GRAPHS * 64);  // N
    int*   rowptr = deg + N_NODES;                           // N+4
    int*   bsum   = rowptr + N_NODES + 4;                    // 120 (pad)
    int*   gcur   = bsum + 120;                              // 8
    int*   scur   = gcur + 8;                                // 784 (pad)
    int*   nbr    = scur + 784;                              // E + 8N + 16
    int2*  epair1 = (int2*)(nbr + E_EDGES + 8 * N_NODES + 16);  // 8*BCAP pairs
    int2*  epair2 = epair1 + (size_t)8 * BCAP;               // NSTRIPE*SCAP pairs

    const int* src = ei;
    const int* dst = ei + E_EDGES;

    (void)hipMemsetAsync(d_out, 0, (size_t)G_GRAPHS * OUT_F * sizeof(float), stream);
    (void)hipMemsetAsync(deg, 0, (size_t)N_NODES * sizeof(int), stream);

    deg_kernel<<<(E_EDGES / 4 + 255) / 256, 256, 0, stream>>>(dst, deg);
    scanA_kernel<<<SCAN_BLOCKS, 256, 0, stream>>>(deg, bsum);
    scanB_kernel<<<1, 128, 0, stream>>>(bsum, rowptr, gcur);
    scanC_kernel<<<SCAN_BLOCKS, 256, 0, stream>>>(deg, bsum, rowptr, scur);
    fillA_kernel<<<NCHUNK, 256, 0, stream>>>(src, dst, gcur, epair1);
    fillB2_kernel<<<FB_GRID, 256, 0, stream>>>(epair1, gcur, scur, epair2);
    fillC_kernel<<<NSTRIPE, 256, 0, stream>>>(epair2, scur, rowptr, nbr);
    tobf_kernel<<<(N_NODES * 8 + 255) / 256, 256, 0, stream>>>(x, XBF);

    int nb = (N_NODES + 63) / 64;

    for (int l = 0; l < L_LAYERS; ++l) {
        // stats (128) + pooled (G*64) are adjacent: one memset
        (void)hipMemsetAsync(stats, 0, (128 + (size_t)G_GRAPHS * 64) * sizeof(float), stream);

        gemm1_fused_kernel<<<nb, 256, 0, stream>>>(XBF, rowptr, nbr,
            W1 + l * 64 * 64, b1 + l * 64, H16, stats);
        gemm2_pool_kernel<<<nb, 256, 0, stream>>>(H16, stats,
            gamma + l * 64, beta + l * 64, W2 + l * 64 * 64, b2 + l * 64, batch,
            pooled, (unsigned short*)XBF);
        out_kernel<<<(G_GRAPHS * OUT_F + 127) / 128, 128, 0, stream>>>(
            pooled, Wout + l * 64 * OUT_F, bout + l * OUT_F, out);
    }
}

// Round 15
// 355.125 us; speedup vs baseline: 1.4818x; 1.1985x over previous
//
#include <hip/hip_runtime.h>

typedef unsigned int uint;

#define N_NODES 100000
#define E_EDGES 1600000
#define L_LAYERS 3
#define G_GRAPHS 128
#define OUT_F 10
#define BN_EPS 1e-5f

#define BSHIFT 7                          // 128-node stripes
#define NSTRIPE ((N_NODES + 127) >> 7)    // 782
#define CHUNK 2048
#define NCHUNK ((E_EDGES + CHUNK - 1) / CHUNK)   // 782
#define PAD8(d) (((d) + 7) & ~7)
#define BCAP (2048 * 103)                 // per-XCD queue capacity (pairs)
#define FB_GRID (103 * 8)
#define SCAP 2560                         // per-stripe queue capacity (pairs; ~11 sd)
#define SNBR 3584                         // per-stripe nbr region (ints, mult of 8)

// bf16 pack (RTNE) / unpack helpers
__device__ __forceinline__ uint bf_pack(float a, float b) {
    uint ua = __float_as_uint(a);
    ua = (ua + 0x7fffu + ((ua >> 16) & 1u)) >> 16;
    uint ub = __float_as_uint(b);
    ub = (ub + 0x7fffu + ((ub >> 16) & 1u)) >> 16;
    return ua | (ub << 16);
}
__device__ __forceinline__ unsigned short bf1(float a) {
    uint ua = __float_as_uint(a);
    return (unsigned short)((ua + 0x7fffu + ((ua >> 16) & 1u)) >> 16);
}
__device__ __forceinline__ float lo16(uint u) { return __uint_as_float(u << 16); }
__device__ __forceinline__ float hi16(uint u) { return __uint_as_float(u & 0xffff0000u); }

// -------------------- init queue cursors ----------------------------------
__global__ __launch_bounds__(256) void init_kernel(int* __restrict__ gcur,
                                                   int* __restrict__ scur) {
    int t = blockIdx.x * 256 + threadIdx.x;
    if (t < 8) gcur[t] = t * BCAP;
    if (t < NSTRIPE) scur[t] = t * SCAP;
}

// ---- fill pass A: bin edges into 8 per-XCD queues (single read of ei) ----
__global__ __launch_bounds__(256) void fillA_kernel(
    const int* __restrict__ src, const int* __restrict__ dst,
    int* __restrict__ gcur, int2* __restrict__ epair) {
    __shared__ int lcnt[8];
    __shared__ int lbase[8];
    int tid = threadIdx.x;
    int base = blockIdx.x * CHUNK;
    if (tid < 8) lcnt[tid] = 0;
    __syncthreads();

    int sd[8], ss[8], bk[8], off[8];
    #pragma unroll
    for (int it = 0; it < 8; ++it) {
        int e = base + it * 256 + tid;
        bk[it] = -1;
        if (e < E_EDGES) {
            sd[it] = dst[e];
            ss[it] = src[e];
            bk[it] = (sd[it] >> BSHIFT) & 7;
            off[it] = atomicAdd(&lcnt[bk[it]], 1);
        }
    }
    __syncthreads();
    if (tid < 8) lbase[tid] = atomicAdd(&gcur[tid], lcnt[tid]);
    __syncthreads();
    #pragma unroll
    for (int it = 0; it < 8; ++it) {
        if (bk[it] >= 0)
            epair[lbase[bk[it]] + off[it]] = make_int2(ss[it], sd[it]);
    }
}

// ---- fill pass B2: bin XCD queue by stripe (98 buckets per XCD) ----------
__global__ __launch_bounds__(256) void fillB2_kernel(
    const int2* __restrict__ epair1, const int* __restrict__ gcur,
    int* __restrict__ scur, int2* __restrict__ epair2) {
    __shared__ int lcnt[98];
    __shared__ int lbase[98];
    int tid = threadIdx.x;
    int g = blockIdx.x & 7;
    int c = blockIdx.x >> 3;
    int ebeg = g * BCAP + c * CHUNK;
    int eend = gcur[g];
    if (tid < 98) lcnt[tid] = 0;
    __syncthreads();

    int2 pp[8]; int bk[8], off[8];
    #pragma unroll
    for (int it = 0; it < 8; ++it) {
        int i = ebeg + it * 256 + tid;
        bk[it] = -1;
        if (i < eend) {
            pp[it] = epair1[i];
            bk[it] = pp[it].y >> 10;               // fine bucket within XCD
            off[it] = atomicAdd(&lcnt[bk[it]], 1);
        }
    }
    __syncthreads();
    if (tid < 98 && lcnt[tid] > 0)
        lbase[tid] = atomicAdd(&scur[(tid << 3) | g], lcnt[tid]);
    __syncthreads();
    #pragma unroll
    for (int it = 0; it < 8; ++it) {
        if (bk[it] >= 0)
            epair2[lbase[bk[it]] + off[it]] = pp[it];
    }
}

// ---- fill pass C2: per-stripe degree-count + scan + place + seq write ----
// Computes per-node rbeg/rend itself (no global histogram/scan needed).
// Stripe s owns fixed nbr region [s*SNBR, s*SNBR+SNBR).
__global__ __launch_bounds__(256) void fillC2_kernel(
    const int2* __restrict__ epair2, const int* __restrict__ scur,
    int* __restrict__ rbeg, int* __restrict__ rend, int* __restrict__ nbr) {
    __shared__ int cnt[128];
    __shared__ int loc[128];
    __shared__ int off[128];
    __shared__ int buf[SNBR];
    __shared__ int stotal;
    int s = blockIdx.x;
    int tid = threadIdx.x;
    int node0 = s << 7;
    int qbeg = s * SCAP;
    int qend = scur[s];                    // base + count after fillB2
    if (tid < 128) cnt[tid] = 0;
    __syncthreads();

    // pass 1: per-node degree count (queue is L2-resident, ~16KB)
    for (int i = qbeg + tid; i < qend; i += 256)
        atomicAdd(&cnt[epair2[i].y & 127], 1);
    __syncthreads();

    // inclusive scan of padded degrees over 128 entries
    int v = (tid < 128) ? PAD8(cnt[tid]) : 0;
    if (tid < 128) loc[tid] = v;
    __syncthreads();
    for (int o = 1; o < 128; o <<= 1) {
        int u = (tid < 128 && tid >= o) ? loc[tid - o] : 0;
        __syncthreads();
        if (tid < 128) loc[tid] += u;
        __syncthreads();
    }
    int sbase = s * SNBR;
    if (tid < 128) {
        int ex = loc[tid] - v;             // exclusive prefix
        off[tid] = ex;
        int node = node0 + tid;
        if (node < N_NODES) {
            rbeg[node] = sbase + ex;
            rend[node] = sbase + ex + v;   // padded end
        }
    }
    if (tid == 0) stotal = loc[127];
    __syncthreads();
    int total = stotal;

    for (int i = tid; i < total; i += 256) buf[i] = N_NODES;   // sentinels
    __syncthreads();

    // pass 2: place edges via LDS cursors
    for (int i = qbeg + tid; i < qend; i += 256) {
        int2 p = epair2[i];
        int pos = atomicAdd(&off[p.y & 127], 1);
        buf[pos] = p.x;
    }
    __syncthreads();

    // sequential int4 write of the whole stripe segment
    for (int i = tid * 4; i < total; i += 1024)
        *reinterpret_cast<int4*>(nbr + sbase + i) = *reinterpret_cast<const int4*>(buf + i);
}

// -------------------- x f32 -> bf16 (layer 0 only) ------------------------
__global__ __launch_bounds__(256) void tobf_kernel(const float* __restrict__ x,
                                                   uint* __restrict__ xbf) {
    int i = blockIdx.x * 256 + threadIdx.x;   // N*8 threads, 8 floats each
    if (i < N_NODES * 8) {
        float4 a = reinterpret_cast<const float4*>(x)[i * 2];
        float4 b = reinterpret_cast<const float4*>(x)[i * 2 + 1];
        uint4 o;
        o.x = bf_pack(a.x, a.y);
        o.y = bf_pack(a.z, a.w);
        o.z = bf_pack(b.x, b.y);
        o.w = bf_pack(b.z, b.w);
        reinterpret_cast<uint4*>(xbf)[i] = o;
    }
    if (i < 8) reinterpret_cast<uint4*>(xbf)[N_NODES * 8 + i] = make_uint4(0, 0, 0, 0);
}

// ------- fused gather(bf16, padded CSR, idx-prefetch) + GEMM1 + stats -----
__global__ __launch_bounds__(256) void gemm1_fused_kernel(
    const uint* __restrict__ xbf, const int* __restrict__ rbeg,
    const int* __restrict__ rend, const int* __restrict__ nbr,
    const float* __restrict__ W1, const float* __restrict__ b1,
    unsigned short* __restrict__ h16, float* __restrict__ stats) {
    __shared__ float sA[64][68];                 // +4 pad: 2-way bank alias (free)
    __shared__ unsigned short sWh[64][64];
    int tid = threadIdx.x;
    int row0 = blockIdx.x * 64;

    for (int i = tid; i < 1024; i += 256) {
        float4 w = reinterpret_cast<const float4*>(W1)[i];
        unsigned short* p = &sWh[0][0] + i * 4;
        p[0] = bf1(w.x); p[1] = bf1(w.y); p[2] = bf1(w.z); p[3] = bf1(w.w);
    }

    const uint4* xb4 = reinterpret_cast<const uint4*>(xbf);
    int c8 = tid & 7;        // uint4 slot within row (8 bf16 cols)
    int rslot = tid >> 3;    // 32 rows per pass
    for (int rr = 0; rr < 2; ++rr) {
        int r = rslot + 32 * rr;
        int gr = row0 + r;
        float a0 = 0.f, a1 = 0.f, a2 = 0.f, a3 = 0.f;
        float a4 = 0.f, a5 = 0.f, a6 = 0.f, a7 = 0.f;
        if (gr < N_NODES) {
            uint4 sv = xb4[(size_t)gr * 8 + c8];
            a0 = lo16(sv.x); a1 = hi16(sv.x); a2 = lo16(sv.y); a3 = hi16(sv.y);
            a4 = lo16(sv.z); a5 = hi16(sv.z); a6 = lo16(sv.w); a7 = hi16(sv.w);
            int beg = rbeg[gr], end = rend[gr];
            int4 ia = *reinterpret_cast<const int4*>(nbr + beg);
            int4 ib = *reinterpret_cast<const int4*>(nbr + beg + 4);
            for (int j = beg; j < end; j += 8) {
                int4 ian = *reinterpret_cast<const int4*>(nbr + j + 8);
                int4 ibn = *reinterpret_cast<const int4*>(nbr + j + 12);
                uint4 v0 = xb4[(size_t)ia.x * 8 + c8];
                uint4 v1 = xb4[(size_t)ia.y * 8 + c8];
                uint4 v2 = xb4[(size_t)ia.z * 8 + c8];
                uint4 v3 = xb4[(size_t)ia.w * 8 + c8];
                uint4 v4 = xb4[(size_t)ib.x * 8 + c8];
                uint4 v5 = xb4[(size_t)ib.y * 8 + c8];
                uint4 v6 = xb4[(size_t)ib.z * 8 + c8];
                uint4 v7 = xb4[(size_t)ib.w * 8 + c8];
                a0 += lo16(v0.x); a1 += hi16(v0.x); a2 += lo16(v0.y); a3 += hi16(v0.y);
                a4 += lo16(v0.z); a5 += hi16(v0.z); a6 += lo16(v0.w); a7 += hi16(v0.w);
                a0 += lo16(v1.x); a1 += hi16(v1.x); a2 += lo16(v1.y); a3 += hi16(v1.y);
                a4 += lo16(v1.z); a5 += hi16(v1.z); a6 += lo16(v1.w); a7 += hi16(v1.w);
                a0 += lo16(v2.x); a1 += hi16(v2.x); a2 += lo16(v2.y); a3 += hi16(v2.y);
                a4 += lo16(v2.z); a5 += hi16(v2.z); a6 += lo16(v2.w); a7 += hi16(v2.w);
                a0 += lo16(v3.x); a1 += hi16(v3.x); a2 += lo16(v3.y); a3 += hi16(v3.y);
                a4 += lo16(v3.z); a5 += hi16(v3.z); a6 += lo16(v3.w); a7 += hi16(v3.w);
                a0 += lo16(v4.x); a1 += hi16(v4.x); a2 += lo16(v4.y); a3 += hi16(v4.y);
                a4 += lo16(v4.z); a5 += hi16(v4.z); a6 += lo16(v4.w); a7 += hi16(v4.w);
                a0 += lo16(v5.x); a1 += hi16(v5.x); a2 += lo16(v5.y); a3 += hi16(v5.y);
                a4 += lo16(v5.z); a5 += hi16(v5.z); a6 += lo16(v5.w); a7 += hi16(v5.w);
                a0 += lo16(v6.x); a1 += hi16(v6.x); a2 += lo16(v6.y); a3 += hi16(v6.y);
                a4 += lo16(v6.z); a5 += hi16(v6.z); a6 += lo16(v6.w); a7 += hi16(v6.w);
                a0 += lo16(v7.x); a1 += hi16(v7.x); a2 += lo16(v7.y); a3 += hi16(v7.y);
                a4 += lo16(v7.z); a5 += hi16(v7.z); a6 += lo16(v7.w); a7 += hi16(v7.w);
                ia = ian; ib = ibn;
            }
        }
        *reinterpret_cast<float4*>(&sA[r][c8 * 8])     = make_float4(a0, a1, a2, a3);
        *reinterpret_cast<float4*>(&sA[r][c8 * 8 + 4]) = make_float4(a4, a5, a6, a7);
    }
    __syncthreads();

    // 4x4 register-tiled GEMM: thread (rt=tid>>4, ct=tid&15)
    int ct = tid & 15, rt = tid >> 4;
    int cbase = ct * 4, rbase = rt * 4;
    float4 bias = reinterpret_cast<const float4*>(b1)[ct];
    float acc[4][4];
    #pragma unroll
    for (int i = 0; i < 4; ++i) {
        acc[i][0] = bias.x; acc[i][1] = bias.y; acc[i][2] = bias.z; acc[i][3] = bias.w;
    }
    for (int k = 0; k < 64; ++k) {
        float A0 = sA[rbase + 0][k], A1 = sA[rbase + 1][k];
        float A2 = sA[rbase + 2][k], A3 = sA[rbase + 3][k];
        uint2 wp = *reinterpret_cast<const uint2*>(&sWh[k][cbase]);
        float w0 = lo16(wp.x), w1 = hi16(wp.x), w2 = lo16(wp.y), w3 = hi16(wp.y);
        acc[0][0] = fmaf(A0, w0, acc[0][0]); acc[0][1] = fmaf(A0, w1, acc[0][1]);
        acc[0][2] = fmaf(A0, w2, acc[0][2]); acc[0][3] = fmaf(A0, w3, acc[0][3]);
        acc[1][0] = fmaf(A1, w0, acc[1][0]); acc[1][1] = fmaf(A1, w1, acc[1][1]);
        acc[1][2] = fmaf(A1, w2, acc[1][2]); acc[1][3] = fmaf(A1, w3, acc[1][3]);
        acc[2][0] = fmaf(A2, w0, acc[2][0]); acc[2][1] = fmaf(A2, w1, acc[2][1]);
        acc[2][2] = fmaf(A2, w2, acc[2][2]); acc[2][3] = fmaf(A2, w3, acc[2][3]);
        acc[3][0] = fmaf(A3, w0, acc[3][0]); acc[3][1] = fmaf(A3, w1, acc[3][1]);
        acc[3][2] = fmaf(A3, w2, acc[3][2]); acc[3][3] = fmaf(A3, w3, acc[3][3]);
    }

    float csum[4] = {0.f, 0.f, 0.f, 0.f};
    float csq[4]  = {0.f, 0.f, 0.f, 0.f};
    #pragma unroll
    for (int i = 0; i < 4; ++i) {
        int gr = row0 + rbase + i;
        if (gr < N_NODES) {
            uint2 o;
            o.x = bf_pack(acc[i][0], acc[i][1]);
            o.y = bf_pack(acc[i][2], acc[i][3]);
            *reinterpret_cast<uint2*>(&h16[(size_t)gr * 64 + cbase]) = o;
            #pragma unroll
            for (int j = 0; j < 4; ++j) {
                csum[j] += acc[i][j];
                csq[j]  += acc[i][j] * acc[i][j];
            }
        }
    }
    __syncthreads();                     // sA reads done; reuse as scratch
    float* scratch = &sA[0][0];
    #pragma unroll
    for (int j = 0; j < 4; ++j) {
        scratch[rt * 136 + cbase + j]      = csum[j];
        scratch[rt * 136 + 64 + cbase + j] = csq[j];
    }
    __syncthreads();
    if (tid < 64) {
        float s = 0.f, q = 0.f;
        #pragma unroll
        for (int r2 = 0; r2 < 16; ++r2) {
            s += scratch[r2 * 136 + tid];
            q += scratch[r2 * 136 + 64 + tid];
        }
        unsafeAtomicAdd(&stats[tid], s);
        unsafeAtomicAdd(&stats[64 + tid], q);
    }
}

// -- GEMM2(4x4 tile) + pool: xn=relu(bn(h))@W2+b2; pooled += xn; xn->bf16 --
__global__ __launch_bounds__(256) void gemm2_pool_kernel(
    const unsigned short* __restrict__ h16, const float* __restrict__ stats,
    const float* __restrict__ gamma, const float* __restrict__ beta,
    const float* __restrict__ W2, const float* __restrict__ b2,
    const int* __restrict__ batch, float* __restrict__ pooled,
    unsigned short* __restrict__ xout) {
    __shared__ float sA[64][68];
    __shared__ unsigned short sWh[64][64];
    int tid = threadIdx.x;
    int row0 = blockIdx.x * 64;

    for (int i = tid; i < 1024; i += 256) {
        float4 w = reinterpret_cast<const float4*>(W2)[i];
        unsigned short* p = &sWh[0][0] + i * 4;
        p[0] = bf1(w.x); p[1] = bf1(w.y); p[2] = bf1(w.z); p[3] = bf1(w.w);
    }

    // per-thread BN scale/shift for its fixed 8 staging columns
    int c8 = tid & 7;
    float scv[8], shv[8];
    #pragma unroll
    for (int k = 0; k < 8; ++k) {
        int col = c8 * 8 + k;
        float mu = stats[col] * (1.0f / N_NODES);
        float var = stats[64 + col] * (1.0f / N_NODES) - mu * mu;
        scv[k] = gamma[col] * rsqrtf(var + BN_EPS);
        shv[k] = beta[col] - mu * scv[k];
    }

    const uint4* h4 = reinterpret_cast<const uint4*>(h16);
    for (int i = tid; i < 512; i += 256) {
        int r = i >> 3;                    // (i&7) == c8 since 256 % 8 == 0
        int gr = row0 + r;
        float o[8] = {0.f, 0.f, 0.f, 0.f, 0.f, 0.f, 0.f, 0.f};
        if (gr < N_NODES) {
            uint4 v = h4[(size_t)gr * 8 + c8];
            float f[8] = {lo16(v.x), hi16(v.x), lo16(v.y), hi16(v.y),
                          lo16(v.z), hi16(v.z), lo16(v.w), hi16(v.w)};
            #pragma unroll
            for (int k = 0; k < 8; ++k)
                o[k] = fmaxf(fmaf(f[k], scv[k], shv[k]), 0.f);
        }
        *reinterpret_cast<float4*>(&sA[r][c8 * 8]) = make_float4(o[0], o[1], o[2], o[3]);
        *reinterpret_cast<float4*>(&sA[r][c8 * 8 + 4]) = make_float4(o[4], o[5], o[6], o[7]);
    }
    __syncthreads();

    int ct = tid & 15, rt = tid >> 4;
    int cbase = ct * 4, rbase = rt * 4;
    float4 bias = reinterpret_cast<const float4*>(b2)[ct];
    float acc[4][4];
    #pragma unroll
    for (int i = 0; i < 4; ++i) {
        acc[i][0] = bias.x; acc[i][1] = bias.y; acc[i][2] = bias.z; acc[i][3] = bias.w;
    }
    for (int k = 0; k < 64; ++k) {
        float A0 = sA[rbase + 0][k], A1 = sA[rbase + 1][k];
        float A2 = sA[rbase + 2][k], A3 = sA[rbase + 3][k];
        uint2 wp = *reinterpret_cast<const uint2*>(&sWh[k][cbase]);
        float w0 = lo16(wp.x), w1 = hi16(wp.x), w2 = lo16(wp.y), w3 = hi16(wp.y);
        acc[0][0] = fmaf(A0, w0, acc[0][0]); acc[0][1] = fmaf(A0, w1, acc[0][1]);
        acc[0][2] = fmaf(A0, w2, acc[0][2]); acc[0][3] = fmaf(A0, w3, acc[0][3]);
        acc[1][0] = fmaf(A1, w0, acc[1][0]); acc[1][1] = fmaf(A1, w1, acc[1][1]);
        acc[1][2] = fmaf(A1, w2, acc[1][2]); acc[1][3] = fmaf(A1, w3, acc[1][3]);
        acc[2][0] = fmaf(A2, w0, acc[2][0]); acc[2][1] = fmaf(A2, w1, acc[2][1]);
        acc[2][2] = fmaf(A2, w2, acc[2][2]); acc[2][3] = fmaf(A2, w3, acc[2][3]);
        acc[3][0] = fmaf(A3, w0, acc[3][0]); acc[3][1] = fmaf(A3, w1, acc[3][1]);
        acc[3][2] = fmaf(A3, w2, acc[3][2]); acc[3][3] = fmaf(A3, w3, acc[3][3]);
    }

    // write xout (bf16)
    #pragma unroll
    for (int i = 0; i < 4; ++i) {
        int gr = row0 + rbase + i;
        if (gr < N_NODES) {
            uint2 o;
            o.x = bf_pack(acc[i][0], acc[i][1]);
            o.y = bf_pack(acc[i][2], acc[i][3]);
            *reinterpret_cast<uint2*>(&xout[(size_t)gr * 64 + cbase]) = o;
        }
    }

    // pool: single-graph block -> LDS reduce + 1 atomic/col; else run-length
    int lastrow = row0 + 63; if (lastrow >= N_NODES) lastrow = N_NODES - 1;
    int b0 = batch[row0], bL = batch[lastrow];
    if (b0 == bL) {
        float psum[4] = {0.f, 0.f, 0.f, 0.f};
        #pragma unroll
        for (int i = 0; i < 4; ++i) {
            int gr = row0 + rbase + i;
            if (gr < N_NODES) {
                #pragma unroll
                for (int j = 0; j < 4; ++j) psum[j] += acc[i][j];
            }
        }
        __syncthreads();                 // sA reads done; reuse as scratch
        float* scratch = &sA[0][0];
        #pragma unroll
        for (int j = 0; j < 4; ++j) scratch[rt * 68 + cbase + j] = psum[j];
        __syncthreads();
        if (tid < 64) {
            float s = 0.f;
            #pragma unroll
            for (int r2 = 0; r2 < 16; ++r2) s += scratch[r2 * 68 + tid];
            unsafeAtomicAdd(&pooled[b0 * 64 + tid], s);
        }
    } else {
        #pragma unroll
        for (int j = 0; j < 4; ++j) {
            float pacc = 0.f;
            int curb = -1;
            #pragma unroll
            for (int i = 0; i < 4; ++i) {
                int gr = row0 + rbase + i;
                if (gr < N_NODES) {
                    int b = batch[gr];
                    if (b != curb) {
                        if (curb >= 0) unsafeAtomicAdd(&pooled[curb * 64 + cbase + j], pacc);
                        curb = b;
                        pacc = 0.f;
                    }
                    pacc += acc[i][j];
                }
            }
            if (curb >= 0) unsafeAtomicAdd(&pooled[curb * 64 + cbase + j], pacc);
        }
    }
}

// -------------------- output: score += pooled @ Wout + bout --------------
__global__ void out_kernel(const float* __restrict__ pooled,
                           const float* __restrict__ Wout,
                           const float* __restrict__ bout,
                           float* __restrict__ score) {
    int idx = blockIdx.x * blockDim.x + threadIdx.x;
    if (idx >= G_GRAPHS * OUT_F) return;
    int g = idx / OUT_F;
    int o = idx - g * OUT_F;
    float acc = bout[o];
    #pragma unroll
    for (int k = 0; k < 64; ++k) acc += pooled[g * 64 + k] * Wout[k * OUT_F + o];
    score[idx] += acc;
}

extern "C" void kernel_launch(void* const* d_in, const int* in_sizes, int n_in,
                              void* d_out, int out_size, void* d_ws, size_t ws_size,
                              hipStream_t stream) {
    const float* x     = (const float*)d_in[0];
    const int*   ei    = (const int*)d_in[1];
    const int*   batch = (const int*)d_in[2];
    const float* W1    = (const float*)d_in[3];
    const float* b1    = (const float*)d_in[4];
    const float* gamma = (const float*)d_in[5];
    const float* beta  = (const float*)d_in[6];
    const float* W2    = (const float*)d_in[7];
    const float* b2    = (const float*)d_in[8];
    const float* Wout  = (const float*)d_in[9];
    const float* bout  = (const float*)d_in[10];
    float* out = (float*)d_out;

    unsigned short* H16 = (unsigned short*)d_ws;             // N*64 bf16
    uint*  XBF    = (uint*)(H16 + (size_t)N_NODES * 64);     // (N+1)*32 uints
    float* stats  = (float*)(XBF + (size_t)(N_NODES + 1) * 32);  // 128
    float* pooled = stats + 128;                             // G*64 (adjacent)
    int*   gcur   = (int*)(pooled + (size_t)G_GRAPHS * 64);  // 8
    int*   scur   = gcur + 8;                                // 784 (pad)
    int*   rbeg   = scur + 784;                              // N
    int*   rend   = rbeg + N_NODES;                          // N
    int*   nbr    = rend + N_NODES;                          // NSTRIPE*SNBR + 16
    int2*  epair1 = (int2*)(nbr + (size_t)NSTRIPE * SNBR + 16);  // 8*BCAP pairs
    int2*  epair2 = epair1 + (size_t)8 * BCAP;               // NSTRIPE*SCAP pairs

    const int* src = ei;
    const int* dst = ei + E_EDGES;

    (void)hipMemsetAsync(d_out, 0, (size_t)G_GRAPHS * OUT_F * sizeof(float), stream);

    init_kernel<<<(NSTRIPE + 255) / 256, 256, 0, stream>>>(gcur, scur);
    fillA_kernel<<<NCHUNK, 256, 0, stream>>>(src, dst, gcur, epair1);
    fillB2_kernel<<<FB_GRID, 256, 0, stream>>>(epair1, gcur, scur, epair2);
    fillC2_kernel<<<NSTRIPE, 256, 0, stream>>>(epair2, scur, rbeg, rend, nbr);
    tobf_kernel<<<(N_NODES * 8 + 255) / 256, 256, 0, stream>>>(x, XBF);

    int nb = (N_NODES + 63) / 64;

    for (int l = 0; l < L_LAYERS; ++l) {
        // stats (128) + pooled (G*64) are adjacent: one memset
        (void)hipMemsetAsync(stats, 0, (128 + (size_t)G_GRAPHS * 64) * sizeof(float), stream);

        gemm1_fused_kernel<<<nb, 256, 0, stream>>>(XBF, rbeg, rend, nbr,
            W1 + l * 64 * 64, b1 + l * 64, H16, stats);
        gemm2_pool_kernel<<<nb, 256, 0, stream>>>(H16, stats,
            gamma + l * 64, beta + l * 64, W2 + l * 64 * 64, b2 + l * 64, batch,
            pooled, (unsigned short*)XBF);
        out_kernel<<<(G_GRAPHS * OUT_F + 127) / 128, 128, 0, stream>>>(
            pooled, Wout + l * 64 * OUT_F, bout + l * OUT_F, out);
    }
}

// Round 16
// 316.326 us; speedup vs baseline: 1.6636x; 1.1227x over previous
//
#include <hip/hip_runtime.h>

typedef unsigned int uint;
typedef short bf16x8 __attribute__((ext_vector_type(8)));
typedef float f32x4 __attribute__((ext_vector_type(4)));

#define N_NODES 100000
#define E_EDGES 1600000
#define L_LAYERS 3
#define G_GRAPHS 128
#define OUT_F 10
#define BN_EPS 1e-5f

#define BSHIFT 7                          // 128-node stripes
#define NSTRIPE ((N_NODES + 127) >> 7)    // 782
#define CHUNK 2048
#define NCHUNK ((E_EDGES + CHUNK - 1) / CHUNK)   // 782
#define PAD8(d) (((d) + 7) & ~7)
#define BCAP (2048 * 103)                 // per-XCD queue capacity (pairs)
#define FB_GRID (103 * 8)
#define SCAP 2560                         // per-stripe queue capacity (pairs)
#define SNBR 3584                         // per-stripe nbr region (ints)

// bf16 pack (RTNE) / unpack helpers
__device__ __forceinline__ uint bf_pack(float a, float b) {
    uint ua = __float_as_uint(a);
    ua = (ua + 0x7fffu + ((ua >> 16) & 1u)) >> 16;
    uint ub = __float_as_uint(b);
    ub = (ub + 0x7fffu + ((ub >> 16) & 1u)) >> 16;
    return ua | (ub << 16);
}
__device__ __forceinline__ unsigned short bf1(float a) {
    uint ua = __float_as_uint(a);
    return (unsigned short)((ua + 0x7fffu + ((ua >> 16) & 1u)) >> 16);
}
__device__ __forceinline__ float lo16(uint u) { return __uint_as_float(u << 16); }
__device__ __forceinline__ float hi16(uint u) { return __uint_as_float(u & 0xffff0000u); }

// -------------------- init queue cursors ----------------------------------
__global__ __launch_bounds__(256) void init_kernel(int* __restrict__ gcur,
                                                   int* __restrict__ scur) {
    int t = blockIdx.x * 256 + threadIdx.x;
    if (t < 8) gcur[t] = t * BCAP;
    if (t < NSTRIPE) scur[t] = t * SCAP;
}

// ---- fill pass A: bin edges into 8 per-XCD queues (single read of ei) ----
__global__ __launch_bounds__(256) void fillA_kernel(
    const int* __restrict__ src, const int* __restrict__ dst,
    int* __restrict__ gcur, int2* __restrict__ epair) {
    __shared__ int lcnt[8];
    __shared__ int lbase[8];
    int tid = threadIdx.x;
    int base = blockIdx.x * CHUNK;
    if (tid < 8) lcnt[tid] = 0;
    __syncthreads();

    int sd[8], ss[8], bk[8], off[8];
    #pragma unroll
    for (int it = 0; it < 8; ++it) {
        int e = base + it * 256 + tid;
        bk[it] = -1;
        if (e < E_EDGES) {
            sd[it] = dst[e];
            ss[it] = src[e];
            bk[it] = (sd[it] >> BSHIFT) & 7;
            off[it] = atomicAdd(&lcnt[bk[it]], 1);
        }
    }
    __syncthreads();
    if (tid < 8) lbase[tid] = atomicAdd(&gcur[tid], lcnt[tid]);
    __syncthreads();
    #pragma unroll
    for (int it = 0; it < 8; ++it) {
        if (bk[it] >= 0)
            epair[lbase[bk[it]] + off[it]] = make_int2(ss[it], sd[it]);
    }
}

// ---- fill pass B2: bin XCD queue by stripe (98 buckets per XCD) ----------
__global__ __launch_bounds__(256) void fillB2_kernel(
    const int2* __restrict__ epair1, const int* __restrict__ gcur,
    int* __restrict__ scur, int2* __restrict__ epair2) {
    __shared__ int lcnt[98];
    __shared__ int lbase[98];
    int tid = threadIdx.x;
    int g = blockIdx.x & 7;
    int c = blockIdx.x >> 3;
    int ebeg = g * BCAP + c * CHUNK;
    int eend = gcur[g];
    if (tid < 98) lcnt[tid] = 0;
    __syncthreads();

    int2 pp[8]; int bk[8], off[8];
    #pragma unroll
    for (int it = 0; it < 8; ++it) {
        int i = ebeg + it * 256 + tid;
        bk[it] = -1;
        if (i < eend) {
            pp[it] = epair1[i];
            bk[it] = pp[it].y >> 10;               // fine bucket within XCD
            off[it] = atomicAdd(&lcnt[bk[it]], 1);
        }
    }
    __syncthreads();
    if (tid < 98 && lcnt[tid] > 0)
        lbase[tid] = atomicAdd(&scur[(tid << 3) | g], lcnt[tid]);
    __syncthreads();
    #pragma unroll
    for (int it = 0; it < 8; ++it) {
        if (bk[it] >= 0)
            epair2[lbase[bk[it]] + off[it]] = pp[it];
    }
}

// ---- fill pass C2: per-stripe degree-count + scan + place + seq write ----
__global__ __launch_bounds__(256) void fillC2_kernel(
    const int2* __restrict__ epair2, const int* __restrict__ scur,
    int* __restrict__ rbeg, int* __restrict__ rend, int* __restrict__ nbr) {
    __shared__ int cnt[128];
    __shared__ int loc[128];
    __shared__ int off[128];
    __shared__ int buf[SNBR];
    __shared__ int stotal;
    int s = blockIdx.x;
    int tid = threadIdx.x;
    int node0 = s << 7;
    int qbeg = s * SCAP;
    int qend = scur[s];                    // base + count after fillB2
    if (tid < 128) cnt[tid] = 0;
    __syncthreads();

    for (int i = qbeg + tid; i < qend; i += 256)
        atomicAdd(&cnt[epair2[i].y & 127], 1);
    __syncthreads();

    int v = (tid < 128) ? PAD8(cnt[tid]) : 0;
    if (tid < 128) loc[tid] = v;
    __syncthreads();
    for (int o = 1; o < 128; o <<= 1) {
        int u = (tid < 128 && tid >= o) ? loc[tid - o] : 0;
        __syncthreads();
        if (tid < 128) loc[tid] += u;
        __syncthreads();
    }
    int sbase = s * SNBR;
    if (tid < 128) {
        int ex = loc[tid] - v;             // exclusive prefix
        off[tid] = ex;
        int node = node0 + tid;
        if (node < N_NODES) {
            rbeg[node] = sbase + ex;
            rend[node] = sbase + ex + v;   // padded end
        }
    }
    if (tid == 0) stotal = loc[127];
    __syncthreads();
    int total = stotal;

    for (int i = tid; i < total; i += 256) buf[i] = N_NODES;   // sentinels
    __syncthreads();

    for (int i = qbeg + tid; i < qend; i += 256) {
        int2 p = epair2[i];
        int pos = atomicAdd(&off[p.y & 127], 1);
        buf[pos] = p.x;
    }
    __syncthreads();

    for (int i = tid * 4; i < total; i += 1024)
        *reinterpret_cast<int4*>(nbr + sbase + i) = *reinterpret_cast<const int4*>(buf + i);
}

// -------------------- x f32 -> bf16 (layer 0 only) ------------------------
__global__ __launch_bounds__(256) void tobf_kernel(const float* __restrict__ x,
                                                   uint* __restrict__ xbf) {
    int i = blockIdx.x * 256 + threadIdx.x;   // N*8 threads, 8 floats each
    if (i < N_NODES * 8) {
        float4 a = reinterpret_cast<const float4*>(x)[i * 2];
        float4 b = reinterpret_cast<const float4*>(x)[i * 2 + 1];
        uint4 o;
        o.x = bf_pack(a.x, a.y);
        o.y = bf_pack(a.z, a.w);
        o.z = bf_pack(b.x, b.y);
        o.w = bf_pack(b.z, b.w);
        reinterpret_cast<uint4*>(xbf)[i] = o;
    }
    if (i < 8) reinterpret_cast<uint4*>(xbf)[N_NODES * 8 + i] = make_uint4(0, 0, 0, 0);
}

// ------- fused gather(bf16, padded CSR) + MFMA GEMM1 + BN stats -----------
__global__ __launch_bounds__(256) void gemm1_fused_kernel(
    const uint* __restrict__ xbf, const int* __restrict__ rbeg,
    const int* __restrict__ rend, const int* __restrict__ nbr,
    const float* __restrict__ W1, const float* __restrict__ b1,
    unsigned short* __restrict__ h16, float* __restrict__ stats) {
    __shared__ unsigned short sA[64][72];        // bf16 agg tile (pad: 2-way alias)
    __shared__ unsigned short sW[64][72];        // bf16 W^T [col][k]
    int tid = threadIdx.x;
    int row0 = blockIdx.x * 64;

    // stage W1 transposed to [col][k]
    for (int i = tid; i < 1024; i += 256) {
        int k = i >> 4, cb = (i & 15) * 4;
        float4 w = reinterpret_cast<const float4*>(W1)[i];
        sW[cb + 0][k] = bf1(w.x);
        sW[cb + 1][k] = bf1(w.y);
        sW[cb + 2][k] = bf1(w.z);
        sW[cb + 3][k] = bf1(w.w);
    }

    const uint4* xb4 = reinterpret_cast<const uint4*>(xbf);
    int c8 = tid & 7;        // uint4 slot within row (8 bf16 cols)
    int rslot = tid >> 3;    // 32 rows per pass
    for (int rr = 0; rr < 2; ++rr) {
        int r = rslot + 32 * rr;
        int gr = row0 + r;
        float a0 = 0.f, a1 = 0.f, a2 = 0.f, a3 = 0.f;
        float a4 = 0.f, a5 = 0.f, a6 = 0.f, a7 = 0.f;
        if (gr < N_NODES) {
            uint4 sv = xb4[(size_t)gr * 8 + c8];
            a0 = lo16(sv.x); a1 = hi16(sv.x); a2 = lo16(sv.y); a3 = hi16(sv.y);
            a4 = lo16(sv.z); a5 = hi16(sv.z); a6 = lo16(sv.w); a7 = hi16(sv.w);
            int beg = rbeg[gr], end = rend[gr];
            int4 ia = *reinterpret_cast<const int4*>(nbr + beg);
            int4 ib = *reinterpret_cast<const int4*>(nbr + beg + 4);
            for (int j = beg; j < end; j += 8) {
                int4 ian = *reinterpret_cast<const int4*>(nbr + j + 8);
                int4 ibn = *reinterpret_cast<const int4*>(nbr + j + 12);
                uint4 v0 = xb4[(size_t)ia.x * 8 + c8];
                uint4 v1 = xb4[(size_t)ia.y * 8 + c8];
                uint4 v2 = xb4[(size_t)ia.z * 8 + c8];
                uint4 v3 = xb4[(size_t)ia.w * 8 + c8];
                uint4 v4 = xb4[(size_t)ib.x * 8 + c8];
                uint4 v5 = xb4[(size_t)ib.y * 8 + c8];
                uint4 v6 = xb4[(size_t)ib.z * 8 + c8];
                uint4 v7 = xb4[(size_t)ib.w * 8 + c8];
                a0 += lo16(v0.x); a1 += hi16(v0.x); a2 += lo16(v0.y); a3 += hi16(v0.y);
                a4 += lo16(v0.z); a5 += hi16(v0.z); a6 += lo16(v0.w); a7 += hi16(v0.w);
                a0 += lo16(v1.x); a1 += hi16(v1.x); a2 += lo16(v1.y); a3 += hi16(v1.y);
                a4 += lo16(v1.z); a5 += hi16(v1.z); a6 += lo16(v1.w); a7 += hi16(v1.w);
                a0 += lo16(v2.x); a1 += hi16(v2.x); a2 += lo16(v2.y); a3 += hi16(v2.y);
                a4 += lo16(v2.z); a5 += hi16(v2.z); a6 += lo16(v2.w); a7 += hi16(v2.w);
                a0 += lo16(v3.x); a1 += hi16(v3.x); a2 += lo16(v3.y); a3 += hi16(v3.y);
                a4 += lo16(v3.z); a5 += hi16(v3.z); a6 += lo16(v3.w); a7 += hi16(v3.w);
                a0 += lo16(v4.x); a1 += hi16(v4.x); a2 += lo16(v4.y); a3 += hi16(v4.y);
                a4 += lo16(v4.z); a5 += hi16(v4.z); a6 += lo16(v4.w); a7 += hi16(v4.w);
                a0 += lo16(v5.x); a1 += hi16(v5.x); a2 += lo16(v5.y); a3 += hi16(v5.y);
                a4 += lo16(v5.z); a5 += hi16(v5.z); a6 += lo16(v5.w); a7 += hi16(v5.w);
                a0 += lo16(v6.x); a1 += hi16(v6.x); a2 += lo16(v6.y); a3 += hi16(v6.y);
                a4 += lo16(v6.z); a5 += hi16(v6.z); a6 += lo16(v6.w); a7 += hi16(v6.w);
                a0 += lo16(v7.x); a1 += hi16(v7.x); a2 += lo16(v7.y); a3 += hi16(v7.y);
                a4 += lo16(v7.z); a5 += hi16(v7.z); a6 += lo16(v7.w); a7 += hi16(v7.w);
                ia = ian; ib = ibn;
            }
        }
        uint4 o;
        o.x = bf_pack(a0, a1); o.y = bf_pack(a2, a3);
        o.z = bf_pack(a4, a5); o.w = bf_pack(a6, a7);
        *reinterpret_cast<uint4*>(&sA[r][c8 * 8]) = o;
    }
    __syncthreads();

    // MFMA GEMM: wave w owns rows [16w,16w+16); 4 col-tiles x 2 K-chunks
    int w = tid >> 6;
    int l = tid & 63;
    int lr = l & 15;         // A-row within tile / D-col
    int lk = l >> 4;         // k-group / D row-group
    f32x4 acc[4];
    #pragma unroll
    for (int ct = 0; ct < 4; ++ct) {
        float b = b1[ct * 16 + lr];
        acc[ct] = (f32x4){b, b, b, b};
    }
    #pragma unroll
    for (int ct = 0; ct < 4; ++ct) {
        #pragma unroll
        for (int kc = 0; kc < 2; ++kc) {
            bf16x8 av = *reinterpret_cast<const bf16x8*>(&sA[w * 16 + lr][kc * 32 + lk * 8]);
            bf16x8 bv = *reinterpret_cast<const bf16x8*>(&sW[ct * 16 + lr][kc * 32 + lk * 8]);
            acc[ct] = __builtin_amdgcn_mfma_f32_16x16x32_bf16(av, bv, acc[ct], 0, 0, 0);
        }
    }

    // epilogue: h16 write + BN stats from accumulators
    float s4[4] = {0.f, 0.f, 0.f, 0.f};   // per-ct col partial sums
    float q4[4] = {0.f, 0.f, 0.f, 0.f};
    #pragma unroll
    for (int ct = 0; ct < 4; ++ct) {
        #pragma unroll
        for (int r = 0; r < 4; ++r) {
            int row = row0 + w * 16 + lk * 4 + r;
            float v = acc[ct][r];
            if (row < N_NODES) {
                h16[(size_t)row * 64 + ct * 16 + lr] = bf1(v);
                s4[ct] += v;
                q4[ct] += v * v;
            }
        }
    }
    __syncthreads();                       // all MFMA reads of sW done
    float* scr = reinterpret_cast<float*>(&sW[0][0]);   // 2048 f32 <= 2304 avail
    int g16 = w * 4 + lk;                  // 0..15
    #pragma unroll
    for (int ct = 0; ct < 4; ++ct) {
        scr[g16 * 64 + ct * 16 + lr] = s4[ct];
        scr[1024 + g16 * 64 + ct * 16 + lr] = q4[ct];
    }
    __syncthreads();
    if (tid < 64) {
        float s = 0.f, q = 0.f;
        #pragma unroll
        for (int r2 = 0; r2 < 16; ++r2) {
            s += scr[r2 * 64 + tid];
            q += scr[1024 + r2 * 64 + tid];
        }
        unsafeAtomicAdd(&stats[tid], s);
        unsafeAtomicAdd(&stats[64 + tid], q);
    }
}

// -- MFMA GEMM2 + pool: xn=relu(bn(h))@W2+b2; pooled += xn; xn->bf16 -------
__global__ __launch_bounds__(256) void gemm2_pool_kernel(
    const unsigned short* __restrict__ h16, const float* __restrict__ stats,
    const float* __restrict__ gamma, const float* __restrict__ beta,
    const float* __restrict__ W2, const float* __restrict__ b2,
    const int* __restrict__ batch, float* __restrict__ pooled,
    unsigned short* __restrict__ xout) {
    __shared__ unsigned short sA[64][72];
    __shared__ unsigned short sW[64][72];
    int tid = threadIdx.x;
    int row0 = blockIdx.x * 64;

    // stage W2 transposed to [col][k]
    for (int i = tid; i < 1024; i += 256) {
        int k = i >> 4, cb = (i & 15) * 4;
        float4 w = reinterpret_cast<const float4*>(W2)[i];
        sW[cb + 0][k] = bf1(w.x);
        sW[cb + 1][k] = bf1(w.y);
        sW[cb + 2][k] = bf1(w.z);
        sW[cb + 3][k] = bf1(w.w);
    }

    // per-thread BN scale/shift for its fixed 8 staging columns
    int c8 = tid & 7;
    float scv[8], shv[8];
    #pragma unroll
    for (int k = 0; k < 8; ++k) {
        int col = c8 * 8 + k;
        float mu = stats[col] * (1.0f / N_NODES);
        float var = stats[64 + col] * (1.0f / N_NODES) - mu * mu;
        scv[k] = gamma[col] * rsqrtf(var + BN_EPS);
        shv[k] = beta[col] - mu * scv[k];
    }

    const uint4* h4 = reinterpret_cast<const uint4*>(h16);
    for (int i = tid; i < 512; i += 256) {
        int r = i >> 3;                    // (i&7) == c8 since 256 % 8 == 0
        int gr = row0 + r;
        float o[8] = {0.f, 0.f, 0.f, 0.f, 0.f, 0.f, 0.f, 0.f};
        if (gr < N_NODES) {
            uint4 v = h4[(size_t)gr * 8 + c8];
            float f[8] = {lo16(v.x), hi16(v.x), lo16(v.y), hi16(v.y),
                          lo16(v.z), hi16(v.z), lo16(v.w), hi16(v.w)};
            #pragma unroll
            for (int k = 0; k < 8; ++k)
                o[k] = fmaxf(fmaf(f[k], scv[k], shv[k]), 0.f);
        }
        uint4 p;
        p.x = bf_pack(o[0], o[1]); p.y = bf_pack(o[2], o[3]);
        p.z = bf_pack(o[4], o[5]); p.w = bf_pack(o[6], o[7]);
        *reinterpret_cast<uint4*>(&sA[r][c8 * 8]) = p;
    }
    __syncthreads();

    int w = tid >> 6;
    int l = tid & 63;
    int lr = l & 15;
    int lk = l >> 4;
    f32x4 acc[4];
    #pragma unroll
    for (int ct = 0; ct < 4; ++ct) {
        float b = b2[ct * 16 + lr];
        acc[ct] = (f32x4){b, b, b, b};
    }
    #pragma unroll
    for (int ct = 0; ct < 4; ++ct) {
        #pragma unroll
        for (int kc = 0; kc < 2; ++kc) {
            bf16x8 av = *reinterpret_cast<const bf16x8*>(&sA[w * 16 + lr][kc * 32 + lk * 8]);
            bf16x8 bv = *reinterpret_cast<const bf16x8*>(&sW[ct * 16 + lr][kc * 32 + lk * 8]);
            acc[ct] = __builtin_amdgcn_mfma_f32_16x16x32_bf16(av, bv, acc[ct], 0, 0, 0);
        }
    }

    // write xout (bf16) from accumulators
    #pragma unroll
    for (int ct = 0; ct < 4; ++ct) {
        #pragma unroll
        for (int r = 0; r < 4; ++r) {
            int row = row0 + w * 16 + lk * 4 + r;
            if (row < N_NODES)
                xout[(size_t)row * 64 + ct * 16 + lr] = bf1(acc[ct][r]);
        }
    }

    // pool
    int lastrow = row0 + 63; if (lastrow >= N_NODES) lastrow = N_NODES - 1;
    int b0 = batch[row0], bL = batch[lastrow];
    if (b0 == bL) {
        float ps[4] = {0.f, 0.f, 0.f, 0.f};
        #pragma unroll
        for (int ct = 0; ct < 4; ++ct) {
            #pragma unroll
            for (int r = 0; r < 4; ++r) {
                int row = row0 + w * 16 + lk * 4 + r;
                if (row < N_NODES) ps[ct] += acc[ct][r];
            }
        }
        __syncthreads();                   // MFMA reads of sW done
        float* scr = reinterpret_cast<float*>(&sW[0][0]);
        int g16 = w * 4 + lk;
        #pragma unroll
        for (int ct = 0; ct < 4; ++ct)
            scr[g16 * 64 + ct * 16 + lr] = ps[ct];
        __syncthreads();
        if (tid < 64) {
            float s = 0.f;
            #pragma unroll
            for (int r2 = 0; r2 < 16; ++r2) s += scr[r2 * 64 + tid];
            unsafeAtomicAdd(&pooled[b0 * 64 + tid], s);
        }
    } else {
        #pragma unroll
        for (int ct = 0; ct < 4; ++ct) {
            float pacc = 0.f;
            int curb = -1;
            int col = ct * 16 + lr;
            #pragma unroll
            for (int r = 0; r < 4; ++r) {
                int row = row0 + w * 16 + lk * 4 + r;
                if (row < N_NODES) {
                    int b = batch[row];
                    if (b != curb) {
                        if (curb >= 0) unsafeAtomicAdd(&pooled[curb * 64 + col], pacc);
                        curb = b;
                        pacc = 0.f;
                    }
                    pacc += acc[ct][r];
                }
            }
            if (curb >= 0) unsafeAtomicAdd(&pooled[curb * 64 + col], pacc);
        }
    }
}

// -------------------- output: score += pooled @ Wout + bout --------------
__global__ void out_kernel(const float* __restrict__ pooled,
                           const float* __restrict__ Wout,
                           const float* __restrict__ bout,
                           float* __restrict__ score) {
    int idx = blockIdx.x * blockDim.x + threadIdx.x;
    if (idx >= G_GRAPHS * OUT_F) return;
    int g = idx / OUT_F;
    int o = idx - g * OUT_F;
    float acc = bout[o];
    #pragma unroll
    for (int k = 0; k < 64; ++k) acc += pooled[g * 64 + k] * Wout[k * OUT_F + o];
    score[idx] += acc;
}

extern "C" void kernel_launch(void* const* d_in, const int* in_sizes, int n_in,
                              void* d_out, int out_size, void* d_ws, size_t ws_size,
                              hipStream_t stream) {
    const float* x     = (const float*)d_in[0];
    const int*   ei    = (const int*)d_in[1];
    const int*   batch = (const int*)d_in[2];
    const float* W1    = (const float*)d_in[3];
    const float* b1    = (const float*)d_in[4];
    const float* gamma = (const float*)d_in[5];
    const float* beta  = (const float*)d_in[6];
    const float* W2    = (const float*)d_in[7];
    const float* b2    = (const float*)d_in[8];
    const float* Wout  = (const float*)d_in[9];
    const float* bout  = (const float*)d_in[10];
    float* out = (float*)d_out;

    unsigned short* H16 = (unsigned short*)d_ws;             // N*64 bf16
    uint*  XBF    = (uint*)(H16 + (size_t)N_NODES * 64);     // (N+1)*32 uints
    float* stats  = (float*)(XBF + (size_t)(N_NODES + 1) * 32);  // 128
    float* pooled = stats + 128;                             // G*64 (adjacent)
    int*   gcur   = (int*)(pooled + (size_t)G_GRAPHS * 64);  // 8
    int*   scur   = gcur + 8;                                // 784 (pad)
    int*   rbeg   = scur + 784;                              // N
    int*   rend   = rbeg + N_NODES;                          // N
    int*   nbr    = rend + N_NODES;                          // NSTRIPE*SNBR + 16
    int2*  epair1 = (int2*)(nbr + (size_t)NSTRIPE * SNBR + 16);  // 8*BCAP pairs
    int2*  epair2 = epair1 + (size_t)8 * BCAP;               // NSTRIPE*SCAP pairs

    const int* src = ei;
    const int* dst = ei + E_EDGES;

    (void)hipMemsetAsync(d_out, 0, (size_t)G_GRAPHS * OUT_F * sizeof(float), stream);

    init_kernel<<<(NSTRIPE + 255) / 256, 256, 0, stream>>>(gcur, scur);
    fillA_kernel<<<NCHUNK, 256, 0, stream>>>(src, dst, gcur, epair1);
    fillB2_kernel<<<FB_GRID, 256, 0, stream>>>(epair1, gcur, scur, epair2);
    fillC2_kernel<<<NSTRIPE, 256, 0, stream>>>(epair2, scur, rbeg, rend, nbr);
    tobf_kernel<<<(N_NODES * 8 + 255) / 256, 256, 0, stream>>>(x, XBF);

    int nb = (N_NODES + 63) / 64;

    for (int l = 0; l < L_LAYERS; ++l) {
        // stats (128) + pooled (G*64) are adjacent: one memset
        (void)hipMemsetAsync(stats, 0, (128 + (size_t)G_GRAPHS * 64) * sizeof(float), stream);

        gemm1_fused_kernel<<<nb, 256, 0, stream>>>(XBF, rbeg, rend, nbr,
            W1 + l * 64 * 64, b1 + l * 64, H16, stats);
        gemm2_pool_kernel<<<nb, 256, 0, stream>>>(H16, stats,
            gamma + l * 64, beta + l * 64, W2 + l * 64 * 64, b2 + l * 64, batch,
            pooled, (unsigned short*)XBF);
        out_kernel<<<(G_GRAPHS * OUT_F + 127) / 128, 128, 0, stream>>>(
            pooled, Wout + l * 64 * OUT_F, bout + l * OUT_F, out);
    }
}